// Round 5
// baseline (299.931 us; speedup 1.0000x reference)
//
#include <hip/hip_runtime.h>
#include <math.h>

#define H_ 192
#define W_ 192
#define HW_ (H_*W_)      // 36864
#define B_ 2
#define C_ 64
#define NPIX_ (B_*HW_)   // 73728
#define EPSV 1e-5f

typedef short s8v  __attribute__((ext_vector_type(8)));
typedef float f4v  __attribute__((ext_vector_type(4)));

__device__ __forceinline__ unsigned short f2bf(float f) {
    union { float f; unsigned u; } x; x.f = f;
    unsigned r = x.u + 0x7fffu + ((x.u >> 16) & 1u);   // RNE
    return (unsigned short)(r >> 16);
}

// ---------------------------------------------------------------------------
// Fold: w1t[c][o] = w1[o][c];
//       wkT[k][p][c] = bf16( sum_o w2[p,o]*dw[o,c,k] )   (p=out-ch, c=in-ch)
//       beff[p] = sum_o w2[p,o]*db[o] + b2[p]
// ---------------------------------------------------------------------------
__global__ void k_fold(const float* __restrict__ w1, const float* __restrict__ w2,
                       const float* __restrict__ dw, const float* __restrict__ db,
                       const float* __restrict__ b2,
                       float* __restrict__ w1t, unsigned short* __restrict__ wkT,
                       float* __restrict__ beff)
{
    int tid = blockIdx.x * 256 + threadIdx.x;   // 0..36863
    if (tid < 9 * 64 * 64) {
        int k = tid >> 12;
        int r = tid & 4095;
        int c = r >> 6;
        int p = r & 63;
        float acc = 0.f;
        #pragma unroll 8
        for (int o = 0; o < 64; ++o)
            acc = fmaf(w2[p * 64 + o], dw[(o * 64 + c) * 9 + k], acc);
        wkT[(k << 12) + (p << 6) + c] = f2bf(acc);
    }
    if (tid < 4096) {
        int c = tid >> 6, o = tid & 63;
        w1t[c * 64 + o] = w1[o * 64 + c];
    }
    if (tid < 64) {
        float acc = b2[tid];
        #pragma unroll 8
        for (int o = 0; o < 64; ++o) acc = fmaf(w2[tid * 64 + o], db[o], acc);
        beff[tid] = acc;
    }
}

// ---------------------------------------------------------------------------
// conv1x1 #1 (fp32 VALU): y = x * w1t + b1  (raw, pre-BN)
// ---------------------------------------------------------------------------
__global__ __launch_bounds__(256) void k_conv1x1(const float* __restrict__ x,
        const float* __restrict__ w1t, const float* __restrict__ b1,
        float* __restrict__ y)
{
    __shared__ __align__(16) float xs[64][64];   // [c][p]
    __shared__ __align__(16) float wsh[64][64];  // [c][o]
    int t = threadIdx.x;
    int base = blockIdx.x * 64;
    int b = base / HW_;
    int hw0 = base % HW_;

    #pragma unroll
    for (int i = 0; i < 16; ++i) {
        int e = t + i * 256;
        ((float*)wsh)[e] = w1t[e];
    }
    int p = t & 63, cg = t >> 6;
    #pragma unroll
    for (int i = 0; i < 16; ++i) {
        int c = cg * 16 + i;
        xs[c][p] = x[(b * 64 + c) * HW_ + hw0 + p];
    }
    __syncthreads();

    int l = t & 63, wv = t >> 6;
    int pg = l & 15;
    int og = wv * 4 + (l >> 4);
    float acc[4][4];
    #pragma unroll
    for (int i = 0; i < 4; ++i)
        #pragma unroll
        for (int j = 0; j < 4; ++j) acc[i][j] = 0.f;

    #pragma unroll 8
    for (int c = 0; c < 64; ++c) {
        float va[4], wa[4];
        *(float4*)va = *(const float4*)&xs[c][pg * 4];
        *(float4*)wa = *(const float4*)&wsh[c][og * 4];
        #pragma unroll
        for (int i = 0; i < 4; ++i)
            #pragma unroll
            for (int j = 0; j < 4; ++j)
                acc[i][j] = fmaf(va[i], wa[j], acc[i][j]);
    }

    #pragma unroll
    for (int j = 0; j < 4; ++j) {
        int oc = og * 4 + j;
        float bias = b1[oc];
        float4 o4 = make_float4(acc[0][j] + bias, acc[1][j] + bias,
                                acc[2][j] + bias, acc[3][j] + bias);
        *(float4*)&y[(b * 64 + oc) * HW_ + hw0 + pg * 4] = o4;
    }
}

// ---------------------------------------------------------------------------
// BN stats: one block per channel; writes scale, shift
// ---------------------------------------------------------------------------
__global__ void k_stats(const float* __restrict__ y, const float* __restrict__ g,
                        const float* __restrict__ be, float* __restrict__ scsh)
{
    int c = blockIdx.x;
    int t = threadIdx.x;
    float s = 0.f, sq = 0.f;
    for (int b = 0; b < B_; ++b) {
        const float4* p4 = (const float4*)&y[(b * 64 + c) * HW_];
        for (int i = t; i < HW_ / 4; i += 256) {
            float4 v = p4[i];
            s += v.x + v.y + v.z + v.w;
            sq += v.x * v.x + v.y * v.y + v.z * v.z + v.w * v.w;
        }
    }
    int lane = t & 63, wv = t >> 6;
    #pragma unroll
    for (int off = 32; off > 0; off >>= 1) {
        s += __shfl_down(s, off);
        sq += __shfl_down(sq, off);
    }
    __shared__ float red[8];
    if (lane == 0) { red[wv] = s; red[4 + wv] = sq; }
    __syncthreads();
    if (t == 0) {
        float S = red[0] + red[1] + red[2] + red[3];
        float Q = red[4] + red[5] + red[6] + red[7];
        float m = S / (float)NPIX_;
        float var = Q / (float)NPIX_ - m * m;
        float sc = g[c] * rsqrtf(var + EPSV);
        scsh[c] = sc;
        scsh[64 + c] = be[c] - m * sc;
    }
}

// ---------------------------------------------------------------------------
// BN apply (optional ReLU), in place, float4
// ---------------------------------------------------------------------------
__global__ void k_bn(float* __restrict__ y, const float* __restrict__ scsh, int relu)
{
    int idx = blockIdx.x * 256 + threadIdx.x;         // float4 index
    int c = ((idx * 4) / HW_) & 63;
    float sc = scsh[c], sh = scsh[64 + c];
    float4 v = ((float4*)y)[idx];
    v.x = fmaf(v.x, sc, sh);
    v.y = fmaf(v.y, sc, sh);
    v.z = fmaf(v.z, sc, sh);
    v.w = fmaf(v.w, sc, sh);
    if (relu) {
        v.x = fmaxf(v.x, 0.f); v.y = fmaxf(v.y, 0.f);
        v.z = fmaxf(v.z, 0.f); v.w = fmaxf(v.w, 0.f);
    }
    ((float4*)y)[idx] = v;
}

// ---------------------------------------------------------------------------
// offset conv3x3 on Abn (BN1+ReLU already applied in place): zero pad 1
// ---------------------------------------------------------------------------
__global__ __launch_bounds__(256) void k_offconv(const float* __restrict__ A,
        const float* __restrict__ ow, const float* __restrict__ ob,
        float* __restrict__ off)
{
    __shared__ float As[16 * 18 * 18];   // [c][r][col]
    __shared__ float wsh[16 * 9 * 20];   // [c][tap][oc pad20]
    int t = threadIdx.x;
    int wg = blockIdx.x;
    int bid = (wg & 7) * 36 + (wg >> 3);   // XCD-chunked
    int b = bid / 144;
    int tile = bid % 144;
    int ty = tile / 12, tx = tile % 12;
    int y0 = ty * 16, x0 = tx * 16;
    int lx = t & 15, ly = t >> 4;

    float acc[18];
    #pragma unroll
    for (int i = 0; i < 18; ++i) acc[i] = 0.f;

    for (int cg = 0; cg < 4; ++cg) {
        int c0 = cg * 16;
        __syncthreads();
        for (int e = t; e < 16 * 18 * 18; e += 256) {
            int c = e / 324, rem = e % 324;
            int r = rem / 18, col = rem % 18;
            int gy = y0 - 1 + r, gx = x0 - 1 + col;
            float v = 0.f;
            if (gy >= 0 && gy < H_ && gx >= 0 && gx < W_)
                v = A[(b * 64 + c0 + c) * HW_ + gy * W_ + gx];
            As[e] = v;
        }
        for (int e = t; e < 16 * 9 * 18; e += 256) {
            int c = e / 162, rem = e % 162;
            int tap = rem / 18, oc = rem % 18;
            wsh[(c * 9 + tap) * 20 + oc] = ow[((oc * 64) + c0 + c) * 9 + tap];
        }
        __syncthreads();
        for (int c = 0; c < 16; ++c) {
            #pragma unroll
            for (int tap = 0; tap < 9; ++tap) {
                int ky = tap / 3, kx = tap % 3;
                float a = As[c * 324 + (ly + ky) * 18 + (lx + kx)];
                const float* wr = &wsh[(c * 9 + tap) * 20];
                #pragma unroll
                for (int oc = 0; oc < 18; ++oc)
                    acc[oc] = fmaf(a, wr[oc], acc[oc]);
            }
        }
    }
    #pragma unroll
    for (int oc = 0; oc < 18; ++oc)
        off[(b * 18 + oc) * HW_ + (y0 + ly) * W_ + x0 + lx] = acc[oc] + ob[oc];
}

// ---------------------------------------------------------------------------
// deformable conv via bf16 MFMA — BARRIER-FREE, NO LDS.
// Wave wv owns a 16px x 64oc output tile. Lane (m = lane&15, q = lane>>4)
// gathers exactly its MFMA A-fragment channels: [8q,8q+8) and [32+8q,+8)
// for pixel m. W fragments load straight from global wkT (L1/L2-resident).
// Waves never synchronize -> gather latency hidden by free-running waves.
// ---------------------------------------------------------------------------
__global__ __launch_bounds__(256) void k_deform(const float* __restrict__ A,
        const float* __restrict__ off,
        const unsigned short* __restrict__ wkT, const float* __restrict__ beff,
        float* __restrict__ out)
{
    int t = threadIdx.x;
    int wg = blockIdx.x;
    int nid = (wg & 7) * 144 + (wg >> 3);        // XCD-chunked
    int base = nid * 64;
    int b = base / HW_;
    int hw0 = base % HW_;
    int h = hw0 / W_;
    int w0 = hw0 % W_;

    int wv = t >> 6;
    int lane = t & 63;
    int m = lane & 15, q = lane >> 4;
    int pw = wv * 16 + m;            // pixel within the 64-px tile
    int hw = hw0 + pw;               // global pixel (same row h)
    int wx = w0 + pw;                // x coordinate

    const float* Ab = &A[(size_t)b * 64 * HW_];

    f4v acc[4];
    #pragma unroll
    for (int n = 0; n < 4; ++n) acc[n] = (f4v){0.f, 0.f, 0.f, 0.f};

    for (int k = 0; k < 9; ++k) {
        // ---- W fragments for this tap (independent loads, issue early)
        const unsigned short* wkb = wkT + ((size_t)k << 12);
        s8v b0[4], b1[4];
        #pragma unroll
        for (int n = 0; n < 4; ++n) {
            int oc = n * 16 + m;
            b0[n] = *(const s8v*)&wkb[oc * 64 + q * 8];
            b1[n] = *(const s8v*)&wkb[oc * 64 + 32 + q * 8];
        }

        // ---- bilinear setup
        float dy = off[((b * 18) + 2 * k) * HW_ + hw];
        float dx = off[((b * 18) + 2 * k + 1) * HW_ + hw];
        float py = (float)(h + k / 3 - 1) + dy;
        float px = (float)(wx + k % 3 - 1) + dx;
        float fly = floorf(py), flx = floorf(px);
        float fy = py - fly, fx = px - flx;
        int y0i = (int)fly, x0i = (int)flx;
        float w00 = (1.f - fy) * (1.f - fx);
        float w01 = (1.f - fy) * fx;
        float w10 = fy * (1.f - fx);
        float w11 = fy * fx;
        bool yv0 = (y0i >= 0) && (y0i < H_);
        bool yv1 = (y0i + 1 >= 0) && (y0i + 1 < H_);
        bool xv0 = (x0i >= 0) && (x0i < W_);
        bool xv1 = (x0i + 1 >= 0) && (x0i + 1 < W_);
        if (!(yv0 && xv0)) w00 = 0.f;
        if (!(yv0 && xv1)) w01 = 0.f;
        if (!(yv1 && xv0)) w10 = 0.f;
        if (!(yv1 && xv1)) w11 = 0.f;
        int yc0 = min(max(y0i, 0), H_ - 1), yc1 = min(max(y0i + 1, 0), H_ - 1);
        int xc0 = min(max(x0i, 0), W_ - 1), xc1 = min(max(x0i + 1, 0), W_ - 1);
        int i00 = yc0 * W_ + xc0, i01 = yc0 * W_ + xc1;
        int i10 = yc1 * W_ + xc0, i11 = yc1 * W_ + xc1;

        // ---- gather this lane's 16 A-fragment channels
        unsigned pwA[4], pwB[4];
        #pragma unroll
        for (int i = 0; i < 4; ++i) {
            unsigned vA = 0, vB = 0;
            #pragma unroll
            for (int jj = 0; jj < 2; ++jj) {
                int j = 2 * i + jj;
                const float* AcA = Ab + (size_t)(8 * q + j) * HW_;
                float v = AcA[i00] * w00 + AcA[i01] * w01
                        + AcA[i10] * w10 + AcA[i11] * w11;
                vA |= ((unsigned)f2bf(v)) << (16 * jj);
                const float* AcB = Ab + (size_t)(32 + 8 * q + j) * HW_;
                float u = AcB[i00] * w00 + AcB[i01] * w01
                        + AcB[i10] * w10 + AcB[i11] * w11;
                vB |= ((unsigned)f2bf(u)) << (16 * jj);
            }
            pwA[i] = vA; pwB[i] = vB;
        }
        union { unsigned u[4]; s8v v; } ua, ub;
        ua.u[0] = pwA[0]; ua.u[1] = pwA[1]; ua.u[2] = pwA[2]; ua.u[3] = pwA[3];
        ub.u[0] = pwB[0]; ub.u[1] = pwB[1]; ub.u[2] = pwB[2]; ub.u[3] = pwB[3];

        // ---- 8 MFMAs: px rows from A-frag, oc columns from W-frag
        #pragma unroll
        for (int n = 0; n < 4; ++n) {
            acc[n] = __builtin_amdgcn_mfma_f32_16x16x32_bf16(ua.v, b0[n], acc[n], 0, 0, 0);
            acc[n] = __builtin_amdgcn_mfma_f32_16x16x32_bf16(ub.v, b1[n], acc[n], 0, 0, 0);
        }
    }

    // ---- epilogue: C/D layout col(lane&15)=oc-offset m, row=(lane>>4)*4+reg=px
    #pragma unroll
    for (int n = 0; n < 4; ++n) {
        int oc = n * 16 + m;
        float bias = beff[oc];
        #pragma unroll
        for (int r = 0; r < 4; ++r) {
            int pxr = wv * 16 + q * 4 + r;
            out[((size_t)b * 64 + oc) * HW_ + hw0 + pxr] = acc[n][r] + bias;
        }
    }
}

// ---------------------------------------------------------------------------
extern "C" void kernel_launch(void* const* d_in, const int* in_sizes, int n_in,
                              void* d_out, int out_size, void* d_ws, size_t ws_size,
                              hipStream_t stream)
{
    const float* x   = (const float*)d_in[0];
    const float* w1  = (const float*)d_in[1];
    const float* b1  = (const float*)d_in[2];
    const float* g1  = (const float*)d_in[3];
    const float* be1 = (const float*)d_in[4];
    const float* ow  = (const float*)d_in[5];
    const float* ob  = (const float*)d_in[6];
    const float* dw  = (const float*)d_in[7];
    const float* db  = (const float*)d_in[8];
    const float* w2  = (const float*)d_in[9];
    const float* b2  = (const float*)d_in[10];
    const float* g2  = (const float*)d_in[11];
    const float* be2 = (const float*)d_in[12];
    float* out = (float*)d_out;

    float* ws    = (float*)d_ws;
    float* A     = ws;                           // conv1x1 out, then BN'd in place
    float* offb  = A + (size_t)NPIX_ * 64;
    float* w1t   = offb + (size_t)B_ * 18 * HW_;
    unsigned short* wkT = (unsigned short*)(w1t + 4096);   // 9*4096 bf16
    float* beff  = (float*)(wkT + 9 * 4096);     // 64
    float* scsh1 = beff + 64;                    // 128
    float* scsh2 = scsh1 + 128;                  // 128

    hipLaunchKernelGGL(k_fold, dim3(144), dim3(256), 0, stream,
                       w1, w2, dw, db, b2, w1t, wkT, beff);
    hipLaunchKernelGGL(k_conv1x1, dim3(NPIX_ / 64), dim3(256), 0, stream,
                       x, w1t, b1, A);
    hipLaunchKernelGGL(k_stats, dim3(64), dim3(256), 0, stream, A, g1, be1, scsh1);
    hipLaunchKernelGGL(k_bn, dim3((NPIX_ * 64 / 4) / 256), dim3(256), 0, stream,
                       A, scsh1, 1);
    hipLaunchKernelGGL(k_offconv, dim3(288), dim3(256), 0, stream,
                       A, ow, ob, offb);
    hipLaunchKernelGGL(k_deform, dim3(NPIX_ / 64), dim3(256), 0, stream,
                       A, offb, wkT, beff, out);
    hipLaunchKernelGGL(k_stats, dim3(64), dim3(256), 0, stream, out, g2, be2, scsh2);
    hipLaunchKernelGGL(k_bn, dim3((NPIX_ * 64 / 4) / 256), dim3(256), 0, stream,
                       out, scsh2, 0);
}

// Round 6
// 249.008 us; speedup vs baseline: 1.2045x; 1.2045x over previous
//
#include <hip/hip_runtime.h>
#include <math.h>

#define H_ 192
#define W_ 192
#define HW_ (H_*W_)      // 36864
#define B_ 2
#define C_ 64
#define NPIX_ (B_*HW_)   // 73728
#define EPSV 1e-5f

typedef short s8v  __attribute__((ext_vector_type(8)));
typedef float f4v  __attribute__((ext_vector_type(4)));

__device__ __forceinline__ unsigned short f2bf(float f) {
    union { float f; unsigned u; } x; x.f = f;
    unsigned r = x.u + 0x7fffu + ((x.u >> 16) & 1u);   // RNE
    return (unsigned short)(r >> 16);
}
__device__ __forceinline__ float bf2f(unsigned short h) {
    union { unsigned u; float f; } x; x.u = ((unsigned)h) << 16; return x.f;
}

// ---------------------------------------------------------------------------
// Fold: w1t[c][o] = w1[o][c];
//       wkT[k][p][c] = bf16( sum_o w2[p,o]*dw[o,c,k] )   (p=out-ch, c=in-ch)
//       beff[p] = sum_o w2[p,o]*db[o] + b2[p]
// ---------------------------------------------------------------------------
__global__ void k_fold(const float* __restrict__ w1, const float* __restrict__ w2,
                       const float* __restrict__ dw, const float* __restrict__ db,
                       const float* __restrict__ b2,
                       float* __restrict__ w1t, unsigned short* __restrict__ wkT,
                       float* __restrict__ beff)
{
    int tid = blockIdx.x * 256 + threadIdx.x;   // 0..36863
    if (tid < 9 * 64 * 64) {
        int k = tid >> 12;
        int r = tid & 4095;
        int c = r >> 6;
        int p = r & 63;
        float acc = 0.f;
        #pragma unroll 8
        for (int o = 0; o < 64; ++o)
            acc = fmaf(w2[p * 64 + o], dw[(o * 64 + c) * 9 + k], acc);
        wkT[(k << 12) + (p << 6) + c] = f2bf(acc);
    }
    if (tid < 4096) {
        int c = tid >> 6, o = tid & 63;
        w1t[c * 64 + o] = w1[o * 64 + c];
    }
    if (tid < 64) {
        float acc = b2[tid];
        #pragma unroll 8
        for (int o = 0; o < 64; ++o) acc = fmaf(w2[tid * 64 + o], db[o], acc);
        beff[tid] = acc;
    }
}

// ---------------------------------------------------------------------------
// conv1x1 #1 (fp32 VALU): y = x * w1t + b1  (raw, pre-BN)
// ---------------------------------------------------------------------------
__global__ __launch_bounds__(256) void k_conv1x1(const float* __restrict__ x,
        const float* __restrict__ w1t, const float* __restrict__ b1,
        float* __restrict__ y)
{
    __shared__ __align__(16) float xs[64][64];   // [c][p]
    __shared__ __align__(16) float wsh[64][64];  // [c][o]
    int t = threadIdx.x;
    int base = blockIdx.x * 64;
    int b = base / HW_;
    int hw0 = base % HW_;

    #pragma unroll
    for (int i = 0; i < 16; ++i) {
        int e = t + i * 256;
        ((float*)wsh)[e] = w1t[e];
    }
    int p = t & 63, cg = t >> 6;
    #pragma unroll
    for (int i = 0; i < 16; ++i) {
        int c = cg * 16 + i;
        xs[c][p] = x[(b * 64 + c) * HW_ + hw0 + p];
    }
    __syncthreads();

    int l = t & 63, wv = t >> 6;
    int pg = l & 15;
    int og = wv * 4 + (l >> 4);
    float acc[4][4];
    #pragma unroll
    for (int i = 0; i < 4; ++i)
        #pragma unroll
        for (int j = 0; j < 4; ++j) acc[i][j] = 0.f;

    #pragma unroll 8
    for (int c = 0; c < 64; ++c) {
        float va[4], wa[4];
        *(float4*)va = *(const float4*)&xs[c][pg * 4];
        *(float4*)wa = *(const float4*)&wsh[c][og * 4];
        #pragma unroll
        for (int i = 0; i < 4; ++i)
            #pragma unroll
            for (int j = 0; j < 4; ++j)
                acc[i][j] = fmaf(va[i], wa[j], acc[i][j]);
    }

    #pragma unroll
    for (int j = 0; j < 4; ++j) {
        int oc = og * 4 + j;
        float bias = b1[oc];
        float4 o4 = make_float4(acc[0][j] + bias, acc[1][j] + bias,
                                acc[2][j] + bias, acc[3][j] + bias);
        *(float4*)&y[(b * 64 + oc) * HW_ + hw0 + pg * 4] = o4;
    }
}

// ---------------------------------------------------------------------------
// BN stats: one block per channel; writes scale, shift
// ---------------------------------------------------------------------------
__global__ void k_stats(const float* __restrict__ y, const float* __restrict__ g,
                        const float* __restrict__ be, float* __restrict__ scsh)
{
    int c = blockIdx.x;
    int t = threadIdx.x;
    float s = 0.f, sq = 0.f;
    for (int b = 0; b < B_; ++b) {
        const float4* p4 = (const float4*)&y[(b * 64 + c) * HW_];
        for (int i = t; i < HW_ / 4; i += 256) {
            float4 v = p4[i];
            s += v.x + v.y + v.z + v.w;
            sq += v.x * v.x + v.y * v.y + v.z * v.z + v.w * v.w;
        }
    }
    int lane = t & 63, wv = t >> 6;
    #pragma unroll
    for (int off = 32; off > 0; off >>= 1) {
        s += __shfl_down(s, off);
        sq += __shfl_down(sq, off);
    }
    __shared__ float red[8];
    if (lane == 0) { red[wv] = s; red[4 + wv] = sq; }
    __syncthreads();
    if (t == 0) {
        float S = red[0] + red[1] + red[2] + red[3];
        float Q = red[4] + red[5] + red[6] + red[7];
        float m = S / (float)NPIX_;
        float var = Q / (float)NPIX_ - m * m;
        float sc = g[c] * rsqrtf(var + EPSV);
        scsh[c] = sc;
        scsh[64 + c] = be[c] - m * sc;
    }
}

// ---------------------------------------------------------------------------
// BN apply, in place, float4 (used for final BN2 only)
// ---------------------------------------------------------------------------
__global__ void k_bn(float* __restrict__ y, const float* __restrict__ scsh, int relu)
{
    int idx = blockIdx.x * 256 + threadIdx.x;         // float4 index
    int c = ((idx * 4) / HW_) & 63;
    float sc = scsh[c], sh = scsh[64 + c];
    float4 v = ((float4*)y)[idx];
    v.x = fmaf(v.x, sc, sh);
    v.y = fmaf(v.y, sc, sh);
    v.z = fmaf(v.z, sc, sh);
    v.w = fmaf(v.w, sc, sh);
    if (relu) {
        v.x = fmaxf(v.x, 0.f); v.y = fmaxf(v.y, 0.f);
        v.z = fmaxf(v.z, 0.f); v.w = fmaxf(v.w, 0.f);
    }
    ((float4*)y)[idx] = v;
}

// ---------------------------------------------------------------------------
// BN1 apply + ReLU in place (fp32 NCHW, for offconv) AND emit bf16 NHWC copy
// (for deform gather). Thread = 32 channels of one pixel; 576 blocks.
// ---------------------------------------------------------------------------
__global__ __launch_bounds__(256) void k_bntr(float* __restrict__ A,
        const float* __restrict__ scsh, unsigned short* __restrict__ Abf)
{
    __shared__ float scb[64], shb[64];
    int t = threadIdx.x;
    int wg = blockIdx.x;
    int nid = (wg & 7) * 72 + (wg >> 3);     // XCD-chunked over 576
    int base = nid * 128;                    // global pixel base
    int b = base / HW_;
    int hw0 = base % HW_;

    if (t < 64) { scb[t] = scsh[t]; shb[t] = scsh[64 + t]; }
    __syncthreads();

    int pl = t & 127;          // pixel within block
    int chalf = t >> 7;        // 0 or 1 -> channels 32*chalf..+32
    int hw = hw0 + pl;
    size_t gpx = (size_t)base + pl;

    unsigned pk[16];
    #pragma unroll
    for (int c = 0; c < 32; ++c) {
        int ch = chalf * 32 + c;
        size_t idx = ((size_t)(b * 64 + ch)) * HW_ + hw;
        float a = A[idx];
        float v = fmaxf(fmaf(a, scb[ch], shb[ch]), 0.f);
        A[idx] = v;
        unsigned bf = f2bf(v);
        if (c & 1) pk[c >> 1] |= bf << 16; else pk[c >> 1] = bf;
    }
    unsigned short* dst = Abf + (gpx << 6) + chalf * 32;
    #pragma unroll
    for (int j = 0; j < 4; ++j)
        *(int4*)&dst[j * 8] = make_int4((int)pk[4 * j], (int)pk[4 * j + 1],
                                        (int)pk[4 * j + 2], (int)pk[4 * j + 3]);
}

// ---------------------------------------------------------------------------
// offset conv3x3 on BN'd A (fp32 NCHW): zero pad 1
// ---------------------------------------------------------------------------
__global__ __launch_bounds__(256) void k_offconv(const float* __restrict__ A,
        const float* __restrict__ ow, const float* __restrict__ ob,
        float* __restrict__ off)
{
    __shared__ float As[16 * 18 * 18];   // [c][r][col]
    __shared__ float wsh[16 * 9 * 20];   // [c][tap][oc pad20]
    int t = threadIdx.x;
    int wg = blockIdx.x;
    int bid = (wg & 7) * 36 + (wg >> 3);   // XCD-chunked
    int b = bid / 144;
    int tile = bid % 144;
    int ty = tile / 12, tx = tile % 12;
    int y0 = ty * 16, x0 = tx * 16;
    int lx = t & 15, ly = t >> 4;

    float acc[18];
    #pragma unroll
    for (int i = 0; i < 18; ++i) acc[i] = 0.f;

    for (int cg = 0; cg < 4; ++cg) {
        int c0 = cg * 16;
        __syncthreads();
        for (int e = t; e < 16 * 18 * 18; e += 256) {
            int c = e / 324, rem = e % 324;
            int r = rem / 18, col = rem % 18;
            int gy = y0 - 1 + r, gx = x0 - 1 + col;
            float v = 0.f;
            if (gy >= 0 && gy < H_ && gx >= 0 && gx < W_)
                v = A[(b * 64 + c0 + c) * HW_ + gy * W_ + gx];
            As[e] = v;
        }
        for (int e = t; e < 16 * 9 * 18; e += 256) {
            int c = e / 162, rem = e % 162;
            int tap = rem / 18, oc = rem % 18;
            wsh[(c * 9 + tap) * 20 + oc] = ow[((oc * 64) + c0 + c) * 9 + tap];
        }
        __syncthreads();
        for (int c = 0; c < 16; ++c) {
            #pragma unroll
            for (int tap = 0; tap < 9; ++tap) {
                int ky = tap / 3, kx = tap % 3;
                float a = As[c * 324 + (ly + ky) * 18 + (lx + kx)];
                const float* wr = &wsh[(c * 9 + tap) * 20];
                #pragma unroll
                for (int oc = 0; oc < 18; ++oc)
                    acc[oc] = fmaf(a, wr[oc], acc[oc]);
            }
        }
    }
    #pragma unroll
    for (int oc = 0; oc < 18; ++oc)
        off[(b * 18 + oc) * HW_ + (y0 + ly) * W_ + x0 + lx] = acc[oc] + ob[oc];
}

// ---------------------------------------------------------------------------
// deformable conv via bf16 MFMA — barrier-free, no LDS, NHWC-bf16 gather.
// Wave owns 16px x 64oc. Lane (m,q) gathers its A-fragment channels
// [8q,8q+8) and [32+8q,+8) for pixel m: each corner region = ONE dwordx4.
// 8 gather loads/tap/lane (vs 64 scalar in R5), fully coalesced.
// ---------------------------------------------------------------------------
__global__ __launch_bounds__(256) void k_deform(const unsigned short* __restrict__ Abf,
        const float* __restrict__ off,
        const unsigned short* __restrict__ wkT, const float* __restrict__ beff,
        float* __restrict__ out)
{
    int t = threadIdx.x;
    int wg = blockIdx.x;
    int nid = (wg & 7) * 144 + (wg >> 3);        // XCD-chunked
    int base = nid * 64;
    int b = base / HW_;
    int hw0 = base % HW_;
    int h = hw0 / W_;
    int w0 = hw0 % W_;

    int wv = t >> 6;
    int lane = t & 63;
    int m = lane & 15, q = lane >> 4;
    int pw = wv * 16 + m;            // pixel within the 64-px tile
    int hw = hw0 + pw;               // global pixel (same row h)
    int wx = w0 + pw;                // x coordinate

    const unsigned short* Ap = Abf + (((size_t)b * HW_) << 6);
    int cA = q * 8;                  // first A-frag channel group
    int cB = 32 + q * 8;             // second A-frag channel group

    f4v acc[4];
    #pragma unroll
    for (int n = 0; n < 4; ++n) acc[n] = (f4v){0.f, 0.f, 0.f, 0.f};

    for (int k = 0; k < 9; ++k) {
        // ---- W fragments for this tap (L1-resident, identical per block)
        const unsigned short* wkb = wkT + ((size_t)k << 12);
        s8v wb0[4], wb1[4];
        #pragma unroll
        for (int n = 0; n < 4; ++n) {
            int oc = n * 16 + m;
            wb0[n] = *(const s8v*)&wkb[oc * 64 + q * 8];
            wb1[n] = *(const s8v*)&wkb[oc * 64 + 32 + q * 8];
        }

        // ---- bilinear setup
        float dy = off[((b * 18) + 2 * k) * HW_ + hw];
        float dx = off[((b * 18) + 2 * k + 1) * HW_ + hw];
        float py = (float)(h + k / 3 - 1) + dy;
        float px = (float)(wx + k % 3 - 1) + dx;
        float fly = floorf(py), flx = floorf(px);
        float fy = py - fly, fx = px - flx;
        int y0i = (int)fly, x0i = (int)flx;
        float w00 = (1.f - fy) * (1.f - fx);
        float w01 = (1.f - fy) * fx;
        float w10 = fy * (1.f - fx);
        float w11 = fy * fx;
        bool yv0 = (y0i >= 0) && (y0i < H_);
        bool yv1 = (y0i + 1 >= 0) && (y0i + 1 < H_);
        bool xv0 = (x0i >= 0) && (x0i < W_);
        bool xv1 = (x0i + 1 >= 0) && (x0i + 1 < W_);
        if (!(yv0 && xv0)) w00 = 0.f;
        if (!(yv0 && xv1)) w01 = 0.f;
        if (!(yv1 && xv0)) w10 = 0.f;
        if (!(yv1 && xv1)) w11 = 0.f;
        int yc0 = min(max(y0i, 0), H_ - 1), yc1 = min(max(y0i + 1, 0), H_ - 1);
        int xc0 = min(max(x0i, 0), W_ - 1), xc1 = min(max(x0i + 1, 0), W_ - 1);
        size_t i00 = (size_t)(yc0 * W_ + xc0) << 6;
        size_t i01 = (size_t)(yc0 * W_ + xc1) << 6;
        size_t i10 = (size_t)(yc1 * W_ + xc0) << 6;
        size_t i11 = (size_t)(yc1 * W_ + xc1) << 6;

        // ---- 8 coalesced 16B gather loads (4 corners x 2 channel groups)
        s8v v00a = *(const s8v*)&Ap[i00 + cA];
        s8v v01a = *(const s8v*)&Ap[i01 + cA];
        s8v v10a = *(const s8v*)&Ap[i10 + cA];
        s8v v11a = *(const s8v*)&Ap[i11 + cA];
        s8v v00b = *(const s8v*)&Ap[i00 + cB];
        s8v v01b = *(const s8v*)&Ap[i01 + cB];
        s8v v10b = *(const s8v*)&Ap[i10 + cB];
        s8v v11b = *(const s8v*)&Ap[i11 + cB];

        // ---- interp (fp32) + pack to bf16 fragments
        unsigned ua[4], ub[4];
        #pragma unroll
        for (int i = 0; i < 4; ++i) {
            unsigned wa = 0, wbv = 0;
            #pragma unroll
            for (int jj = 0; jj < 2; ++jj) {
                int e = 2 * i + jj;
                float va = bf2f((unsigned short)v00a[e]) * w00
                         + bf2f((unsigned short)v01a[e]) * w01
                         + bf2f((unsigned short)v10a[e]) * w10
                         + bf2f((unsigned short)v11a[e]) * w11;
                wa |= ((unsigned)f2bf(va)) << (16 * jj);
                float vb = bf2f((unsigned short)v00b[e]) * w00
                         + bf2f((unsigned short)v01b[e]) * w01
                         + bf2f((unsigned short)v10b[e]) * w10
                         + bf2f((unsigned short)v11b[e]) * w11;
                wbv |= ((unsigned)f2bf(vb)) << (16 * jj);
            }
            ua[i] = wa; ub[i] = wbv;
        }
        union { unsigned u[4]; s8v v; } fa, fb;
        fa.u[0] = ua[0]; fa.u[1] = ua[1]; fa.u[2] = ua[2]; fa.u[3] = ua[3];
        fb.u[0] = ub[0]; fb.u[1] = ub[1]; fb.u[2] = ub[2]; fb.u[3] = ub[3];

        // ---- 8 MFMAs
        #pragma unroll
        for (int n = 0; n < 4; ++n) {
            acc[n] = __builtin_amdgcn_mfma_f32_16x16x32_bf16(fa.v, wb0[n], acc[n], 0, 0, 0);
            acc[n] = __builtin_amdgcn_mfma_f32_16x16x32_bf16(fb.v, wb1[n], acc[n], 0, 0, 0);
        }
    }

    // ---- epilogue: C/D layout col(lane&15)=oc-offset m, row=(lane>>4)*4+reg=px
    #pragma unroll
    for (int n = 0; n < 4; ++n) {
        int oc = n * 16 + m;
        float bias = beff[oc];
        #pragma unroll
        for (int r = 0; r < 4; ++r) {
            int pxr = wv * 16 + q * 4 + r;
            out[((size_t)b * 64 + oc) * HW_ + hw0 + pxr] = acc[n][r] + bias;
        }
    }
}

// ---------------------------------------------------------------------------
extern "C" void kernel_launch(void* const* d_in, const int* in_sizes, int n_in,
                              void* d_out, int out_size, void* d_ws, size_t ws_size,
                              hipStream_t stream)
{
    const float* x   = (const float*)d_in[0];
    const float* w1  = (const float*)d_in[1];
    const float* b1  = (const float*)d_in[2];
    const float* g1  = (const float*)d_in[3];
    const float* be1 = (const float*)d_in[4];
    const float* ow  = (const float*)d_in[5];
    const float* ob  = (const float*)d_in[6];
    const float* dw  = (const float*)d_in[7];
    const float* db  = (const float*)d_in[8];
    const float* w2  = (const float*)d_in[9];
    const float* b2  = (const float*)d_in[10];
    const float* g2  = (const float*)d_in[11];
    const float* be2 = (const float*)d_in[12];
    float* out = (float*)d_out;

    float* ws    = (float*)d_ws;
    float* A     = ws;                           // conv1x1 out, BN'd in place
    float* offb  = A + (size_t)NPIX_ * 64;       // 1,327,104 floats
    float* w1t   = offb + (size_t)B_ * 18 * HW_;
    unsigned short* wkT = (unsigned short*)(w1t + 4096);   // 36,864 bf16
    float* beff  = (float*)(wkT + 9 * 4096);     // = w1t + 4096 + 18432 floats
    float* scsh1 = beff + 64;                    // 128
    float* scsh2 = scsh1 + 128;                  // 128
    unsigned short* Abf = (unsigned short*)(scsh2 + 128);  // NPIX_*64 bf16 (9.4MB)

    hipLaunchKernelGGL(k_fold, dim3(144), dim3(256), 0, stream,
                       w1, w2, dw, db, b2, w1t, wkT, beff);
    hipLaunchKernelGGL(k_conv1x1, dim3(NPIX_ / 64), dim3(256), 0, stream,
                       x, w1t, b1, A);
    hipLaunchKernelGGL(k_stats, dim3(64), dim3(256), 0, stream, A, g1, be1, scsh1);
    hipLaunchKernelGGL(k_bntr, dim3(NPIX_ / 128), dim3(256), 0, stream,
                       A, scsh1, Abf);
    hipLaunchKernelGGL(k_offconv, dim3(288), dim3(256), 0, stream,
                       A, ow, ob, offb);
    hipLaunchKernelGGL(k_deform, dim3(NPIX_ / 64), dim3(256), 0, stream,
                       Abf, offb, wkT, beff, out);
    hipLaunchKernelGGL(k_stats, dim3(64), dim3(256), 0, stream, out, g2, be2, scsh2);
    hipLaunchKernelGGL(k_bn, dim3((NPIX_ * 64 / 4) / 256), dim3(256), 0, stream,
                       out, scsh2, 0);
}

// Round 7
// 240.881 us; speedup vs baseline: 1.2451x; 1.0337x over previous
//
#include <hip/hip_runtime.h>
#include <math.h>

#define H_ 192
#define W_ 192
#define HW_ (H_*W_)      // 36864
#define B_ 2
#define C_ 64
#define NPIX_ (B_*HW_)   // 73728
#define EPSV 1e-5f

typedef short s8v  __attribute__((ext_vector_type(8)));
typedef float f4v  __attribute__((ext_vector_type(4)));

__device__ __forceinline__ unsigned short f2bf(float f) {
    union { float f; unsigned u; } x; x.f = f;
    unsigned r = x.u + 0x7fffu + ((x.u >> 16) & 1u);   // RNE
    return (unsigned short)(r >> 16);
}
__device__ __forceinline__ float bf2f(unsigned short h) {
    union { unsigned u; float f; } x; x.u = ((unsigned)h) << 16; return x.f;
}

// ---------------------------------------------------------------------------
// Fold: w1t[c][o] = w1[o][c];
//       wkT[k][p][c] = bf16( sum_o w2[p,o]*dw[o,c,k] )   (p=out-ch, c=in-ch)
//       beff[p] = sum_o w2[p,o]*db[o] + b2[p]
// ---------------------------------------------------------------------------
__global__ void k_fold(const float* __restrict__ w1, const float* __restrict__ w2,
                       const float* __restrict__ dw, const float* __restrict__ db,
                       const float* __restrict__ b2,
                       float* __restrict__ w1t, unsigned short* __restrict__ wkT,
                       float* __restrict__ beff)
{
    int tid = blockIdx.x * 256 + threadIdx.x;   // 0..36863
    if (tid < 9 * 64 * 64) {
        int k = tid >> 12;
        int r = tid & 4095;
        int c = r >> 6;
        int p = r & 63;
        float acc = 0.f;
        #pragma unroll 8
        for (int o = 0; o < 64; ++o)
            acc = fmaf(w2[p * 64 + o], dw[(o * 64 + c) * 9 + k], acc);
        wkT[(k << 12) + (p << 6) + c] = f2bf(acc);
    }
    if (tid < 4096) {
        int c = tid >> 6, o = tid & 63;
        w1t[c * 64 + o] = w1[o * 64 + c];
    }
    if (tid < 64) {
        float acc = b2[tid];
        #pragma unroll 8
        for (int o = 0; o < 64; ++o) acc = fmaf(w2[tid * 64 + o], db[o], acc);
        beff[tid] = acc;
    }
}

// ---------------------------------------------------------------------------
// conv1x1 #1 (fp32 VALU): y = x * w1t + b1  (raw, pre-BN)
// ---------------------------------------------------------------------------
__global__ __launch_bounds__(256) void k_conv1x1(const float* __restrict__ x,
        const float* __restrict__ w1t, const float* __restrict__ b1,
        float* __restrict__ y)
{
    __shared__ __align__(16) float xs[64][64];   // [c][p]
    __shared__ __align__(16) float wsh[64][64];  // [c][o]
    int t = threadIdx.x;
    int base = blockIdx.x * 64;
    int b = base / HW_;
    int hw0 = base % HW_;

    #pragma unroll
    for (int i = 0; i < 16; ++i) {
        int e = t + i * 256;
        ((float*)wsh)[e] = w1t[e];
    }
    int p = t & 63, cg = t >> 6;
    #pragma unroll
    for (int i = 0; i < 16; ++i) {
        int c = cg * 16 + i;
        xs[c][p] = x[(b * 64 + c) * HW_ + hw0 + p];
    }
    __syncthreads();

    int l = t & 63, wv = t >> 6;
    int pg = l & 15;
    int og = wv * 4 + (l >> 4);
    float acc[4][4];
    #pragma unroll
    for (int i = 0; i < 4; ++i)
        #pragma unroll
        for (int j = 0; j < 4; ++j) acc[i][j] = 0.f;

    #pragma unroll 8
    for (int c = 0; c < 64; ++c) {
        float va[4], wa[4];
        *(float4*)va = *(const float4*)&xs[c][pg * 4];
        *(float4*)wa = *(const float4*)&wsh[c][og * 4];
        #pragma unroll
        for (int i = 0; i < 4; ++i)
            #pragma unroll
            for (int j = 0; j < 4; ++j)
                acc[i][j] = fmaf(va[i], wa[j], acc[i][j]);
    }

    #pragma unroll
    for (int j = 0; j < 4; ++j) {
        int oc = og * 4 + j;
        float bias = b1[oc];
        float4 o4 = make_float4(acc[0][j] + bias, acc[1][j] + bias,
                                acc[2][j] + bias, acc[3][j] + bias);
        *(float4*)&y[(b * 64 + oc) * HW_ + hw0 + pg * 4] = o4;
    }
}

// ---------------------------------------------------------------------------
// BN stats: one block per channel; writes scale, shift
// ---------------------------------------------------------------------------
__global__ void k_stats(const float* __restrict__ y, const float* __restrict__ g,
                        const float* __restrict__ be, float* __restrict__ scsh)
{
    int c = blockIdx.x;
    int t = threadIdx.x;
    float s = 0.f, sq = 0.f;
    for (int b = 0; b < B_; ++b) {
        const float4* p4 = (const float4*)&y[(b * 64 + c) * HW_];
        for (int i = t; i < HW_ / 4; i += 256) {
            float4 v = p4[i];
            s += v.x + v.y + v.z + v.w;
            sq += v.x * v.x + v.y * v.y + v.z * v.z + v.w * v.w;
        }
    }
    int lane = t & 63, wv = t >> 6;
    #pragma unroll
    for (int off = 32; off > 0; off >>= 1) {
        s += __shfl_down(s, off);
        sq += __shfl_down(sq, off);
    }
    __shared__ float red[8];
    if (lane == 0) { red[wv] = s; red[4 + wv] = sq; }
    __syncthreads();
    if (t == 0) {
        float S = red[0] + red[1] + red[2] + red[3];
        float Q = red[4] + red[5] + red[6] + red[7];
        float m = S / (float)NPIX_;
        float var = Q / (float)NPIX_ - m * m;
        float sc = g[c] * rsqrtf(var + EPSV);
        scsh[c] = sc;
        scsh[64 + c] = be[c] - m * sc;
    }
}

// ---------------------------------------------------------------------------
// BN apply, in place, float4 (used for final BN2 only)
// ---------------------------------------------------------------------------
__global__ void k_bn(float* __restrict__ y, const float* __restrict__ scsh, int relu)
{
    int idx = blockIdx.x * 256 + threadIdx.x;         // float4 index
    int c = ((idx * 4) / HW_) & 63;
    float sc = scsh[c], sh = scsh[64 + c];
    float4 v = ((float4*)y)[idx];
    v.x = fmaf(v.x, sc, sh);
    v.y = fmaf(v.y, sc, sh);
    v.z = fmaf(v.z, sc, sh);
    v.w = fmaf(v.w, sc, sh);
    if (relu) {
        v.x = fmaxf(v.x, 0.f); v.y = fmaxf(v.y, 0.f);
        v.z = fmaxf(v.z, 0.f); v.w = fmaxf(v.w, 0.f);
    }
    ((float4*)y)[idx] = v;
}

// ---------------------------------------------------------------------------
// BN1 apply + ReLU in place (fp32 NCHW, for offconv) AND emit bf16 NHWC copy
// (for deform gather). Thread = 32 channels of one pixel; 576 blocks.
// ---------------------------------------------------------------------------
__global__ __launch_bounds__(256) void k_bntr(float* __restrict__ A,
        const float* __restrict__ scsh, unsigned short* __restrict__ Abf)
{
    __shared__ float scb[64], shb[64];
    int t = threadIdx.x;
    int wg = blockIdx.x;
    int nid = (wg & 7) * 72 + (wg >> 3);     // XCD-chunked over 576
    int base = nid * 128;                    // global pixel base
    int b = base / HW_;
    int hw0 = base % HW_;

    if (t < 64) { scb[t] = scsh[t]; shb[t] = scsh[64 + t]; }
    __syncthreads();

    int pl = t & 127;          // pixel within block
    int chalf = t >> 7;        // 0 or 1 -> channels 32*chalf..+32
    int hw = hw0 + pl;
    size_t gpx = (size_t)base + pl;

    unsigned pk[16];
    #pragma unroll
    for (int c = 0; c < 32; ++c) {
        int ch = chalf * 32 + c;
        size_t idx = ((size_t)(b * 64 + ch)) * HW_ + hw;
        float a = A[idx];
        float v = fmaxf(fmaf(a, scb[ch], shb[ch]), 0.f);
        A[idx] = v;
        unsigned bf = f2bf(v);
        if (c & 1) pk[c >> 1] |= bf << 16; else pk[c >> 1] = bf;
    }
    unsigned short* dst = Abf + (gpx << 6) + chalf * 32;
    #pragma unroll
    for (int j = 0; j < 4; ++j)
        *(int4*)&dst[j * 8] = make_int4((int)pk[4 * j], (int)pk[4 * j + 1],
                                        (int)pk[4 * j + 2], (int)pk[4 * j + 3]);
}

// ---------------------------------------------------------------------------
// offset conv3x3 on BN'd A (fp32 NCHW): zero pad 1
// ---------------------------------------------------------------------------
__global__ __launch_bounds__(256) void k_offconv(const float* __restrict__ A,
        const float* __restrict__ ow, const float* __restrict__ ob,
        float* __restrict__ off)
{
    __shared__ float As[16 * 18 * 18];   // [c][r][col]
    __shared__ float wsh[16 * 9 * 20];   // [c][tap][oc pad20]
    int t = threadIdx.x;
    int wg = blockIdx.x;
    int bid = (wg & 7) * 36 + (wg >> 3);   // XCD-chunked
    int b = bid / 144;
    int tile = bid % 144;
    int ty = tile / 12, tx = tile % 12;
    int y0 = ty * 16, x0 = tx * 16;
    int lx = t & 15, ly = t >> 4;

    float acc[18];
    #pragma unroll
    for (int i = 0; i < 18; ++i) acc[i] = 0.f;

    for (int cg = 0; cg < 4; ++cg) {
        int c0 = cg * 16;
        __syncthreads();
        for (int e = t; e < 16 * 18 * 18; e += 256) {
            int c = e / 324, rem = e % 324;
            int r = rem / 18, col = rem % 18;
            int gy = y0 - 1 + r, gx = x0 - 1 + col;
            float v = 0.f;
            if (gy >= 0 && gy < H_ && gx >= 0 && gx < W_)
                v = A[(b * 64 + c0 + c) * HW_ + gy * W_ + gx];
            As[e] = v;
        }
        for (int e = t; e < 16 * 9 * 18; e += 256) {
            int c = e / 162, rem = e % 162;
            int tap = rem / 18, oc = rem % 18;
            wsh[(c * 9 + tap) * 20 + oc] = ow[((oc * 64) + c0 + c) * 9 + tap];
        }
        __syncthreads();
        for (int c = 0; c < 16; ++c) {
            #pragma unroll
            for (int tap = 0; tap < 9; ++tap) {
                int ky = tap / 3, kx = tap % 3;
                float a = As[c * 324 + (ly + ky) * 18 + (lx + kx)];
                const float* wr = &wsh[(c * 9 + tap) * 20];
                #pragma unroll
                for (int oc = 0; oc < 18; ++oc)
                    acc[oc] = fmaf(a, wr[oc], acc[oc]);
            }
        }
    }
    #pragma unroll
    for (int oc = 0; oc < 18; ++oc)
        off[(b * 18 + oc) * HW_ + (y0 + ly) * W_ + x0 + lx] = acc[oc] + ob[oc];
}

// ---------------------------------------------------------------------------
// deformable conv via bf16 MFMA — 1 wave/block, software-pipelined taps.
// All 18 offsets loaded upfront; gather loads for tap k+1 issued before
// tap k is consumed (2-deep register double buffer, fully unrolled k-loop).
// Lane (m,q): A-frag channels [8q,8q+8) & [32+8q,+8) for pixel m.
// ---------------------------------------------------------------------------
// ISSUE(KK,SS): compute tap-KK bilinear corners + weights, issue 8 gather loads
#define ISSUE(KK, SS) {                                                        \
    float py = (float)(h + (KK) / 3 - 1) + ofy[KK];                            \
    float px = (float)(wx + (KK) % 3 - 1) + ofx[KK];                           \
    float fly = floorf(py), flx = floorf(px);                                  \
    float fy = py - fly, fx = px - flx;                                        \
    int y0i = (int)fly, x0i = (int)flx;                                        \
    float w00 = (1.f - fy) * (1.f - fx);                                       \
    float w01 = (1.f - fy) * fx;                                               \
    float w10 = fy * (1.f - fx);                                               \
    float w11 = fy * fx;                                                       \
    bool yv0 = (y0i >= 0) && (y0i < H_);                                       \
    bool yv1 = (y0i + 1 >= 0) && (y0i + 1 < H_);                               \
    bool xv0 = (x0i >= 0) && (x0i < W_);                                       \
    bool xv1 = (x0i + 1 >= 0) && (x0i + 1 < W_);                               \
    if (!(yv0 && xv0)) w00 = 0.f;                                              \
    if (!(yv0 && xv1)) w01 = 0.f;                                              \
    if (!(yv1 && xv0)) w10 = 0.f;                                              \
    if (!(yv1 && xv1)) w11 = 0.f;                                              \
    int yc0 = min(max(y0i, 0), H_ - 1), yc1 = min(max(y0i + 1, 0), H_ - 1);    \
    int xc0 = min(max(x0i, 0), W_ - 1), xc1 = min(max(x0i + 1, 0), W_ - 1);    \
    size_t i00 = (size_t)(yc0 * W_ + xc0) << 6;                                \
    size_t i01 = (size_t)(yc0 * W_ + xc1) << 6;                                \
    size_t i10 = (size_t)(yc1 * W_ + xc0) << 6;                                \
    size_t i11 = (size_t)(yc1 * W_ + xc1) << 6;                                \
    g00a[SS] = *(const s8v*)&Ap[i00 + cA];                                     \
    g01a[SS] = *(const s8v*)&Ap[i01 + cA];                                     \
    g10a[SS] = *(const s8v*)&Ap[i10 + cA];                                     \
    g11a[SS] = *(const s8v*)&Ap[i11 + cA];                                     \
    g00b[SS] = *(const s8v*)&Ap[i00 + cB];                                     \
    g01b[SS] = *(const s8v*)&Ap[i01 + cB];                                     \
    g10b[SS] = *(const s8v*)&Ap[i10 + cB];                                     \
    g11b[SS] = *(const s8v*)&Ap[i11 + cB];                                     \
    wq0[SS] = w00; wq1[SS] = w01; wq2[SS] = w10; wq3[SS] = w11; }

__global__ __launch_bounds__(64) void k_deform(const unsigned short* __restrict__ Abf,
        const float* __restrict__ off,
        const unsigned short* __restrict__ wkT, const float* __restrict__ beff,
        float* __restrict__ out)
{
    int t = threadIdx.x;
    int wg = blockIdx.x;
    int nid = (wg & 7) * 576 + (wg >> 3);        // XCD-chunked over 4608
    int base = nid * 16;                         // 16-px tile
    int b = base / HW_;
    int hw0 = base % HW_;
    int h = hw0 / W_;
    int w0 = hw0 % W_;

    int m = t & 15, q = t >> 4;
    int hw = hw0 + m;                // this lane's pixel
    int wx = w0 + m;

    const unsigned short* Ap = Abf + (((size_t)b * HW_) << 6);
    int cA = q * 8, cB = 32 + q * 8;

    // ---- all 18 offsets upfront: one memory round trip
    float ofy[9], ofx[9];
    #pragma unroll
    for (int k = 0; k < 9; ++k) {
        ofy[k] = off[((b * 18) + 2 * k) * HW_ + hw];
        ofx[k] = off[((b * 18) + 2 * k + 1) * HW_ + hw];
    }

    f4v acc[4];
    #pragma unroll
    for (int n = 0; n < 4; ++n) acc[n] = (f4v){0.f, 0.f, 0.f, 0.f};

    // ---- gather double buffer (indices constant after full unroll)
    s8v g00a[2], g01a[2], g10a[2], g11a[2];
    s8v g00b[2], g01b[2], g10b[2], g11b[2];
    float wq0[2], wq1[2], wq2[2], wq3[2];

    ISSUE(0, 0);

    #pragma unroll
    for (int k = 0; k < 9; ++k) {
        const int cur = k & 1;
        const int nxt = cur ^ 1;
        if (k < 8) {
            switch (k + 1) {     // keep KK a literal constant for addressing
                case 1: ISSUE(1, nxt); break;
                case 2: ISSUE(2, nxt); break;
                case 3: ISSUE(3, nxt); break;
                case 4: ISSUE(4, nxt); break;
                case 5: ISSUE(5, nxt); break;
                case 6: ISSUE(6, nxt); break;
                case 7: ISSUE(7, nxt); break;
                case 8: ISSUE(8, nxt); break;
            }
        }

        // ---- W fragments for tap k (L2-resident, same for all blocks)
        const unsigned short* wkb = wkT + ((size_t)k << 12);
        s8v wb0[4], wb1[4];
        #pragma unroll
        for (int n = 0; n < 4; ++n) {
            int oc = n * 16 + m;
            wb0[n] = *(const s8v*)&wkb[oc * 64 + q * 8];
            wb1[n] = *(const s8v*)&wkb[oc * 64 + 32 + q * 8];
        }

        // ---- interp (fp32 on bf16 corners) + pack to bf16 fragments
        float w00 = wq0[cur], w01 = wq1[cur], w10 = wq2[cur], w11 = wq3[cur];
        unsigned ua[4], ub[4];
        #pragma unroll
        for (int i = 0; i < 4; ++i) {
            unsigned wa = 0, wbv = 0;
            #pragma unroll
            for (int jj = 0; jj < 2; ++jj) {
                int e = 2 * i + jj;
                float va = bf2f((unsigned short)g00a[cur][e]) * w00
                         + bf2f((unsigned short)g01a[cur][e]) * w01
                         + bf2f((unsigned short)g10a[cur][e]) * w10
                         + bf2f((unsigned short)g11a[cur][e]) * w11;
                wa |= ((unsigned)f2bf(va)) << (16 * jj);
                float vb = bf2f((unsigned short)g00b[cur][e]) * w00
                         + bf2f((unsigned short)g01b[cur][e]) * w01
                         + bf2f((unsigned short)g10b[cur][e]) * w10
                         + bf2f((unsigned short)g11b[cur][e]) * w11;
                wbv |= ((unsigned)f2bf(vb)) << (16 * jj);
            }
            ua[i] = wa; ub[i] = wbv;
        }
        union { unsigned u[4]; s8v v; } fa, fb;
        fa.u[0] = ua[0]; fa.u[1] = ua[1]; fa.u[2] = ua[2]; fa.u[3] = ua[3];
        fb.u[0] = ub[0]; fb.u[1] = ub[1]; fb.u[2] = ub[2]; fb.u[3] = ub[3];

        // ---- 8 MFMAs
        #pragma unroll
        for (int n = 0; n < 4; ++n) {
            acc[n] = __builtin_amdgcn_mfma_f32_16x16x32_bf16(fa.v, wb0[n], acc[n], 0, 0, 0);
            acc[n] = __builtin_amdgcn_mfma_f32_16x16x32_bf16(fb.v, wb1[n], acc[n], 0, 0, 0);
        }
    }

    // ---- epilogue: C/D layout col(lane&15)=oc-offset m, row=(lane>>4)*4+reg=px
    #pragma unroll
    for (int n = 0; n < 4; ++n) {
        int oc = n * 16 + m;
        float bias = beff[oc];
        #pragma unroll
        for (int r = 0; r < 4; ++r) {
            int pxr = q * 4 + r;
            out[((size_t)b * 64 + oc) * HW_ + hw0 + pxr] = acc[n][r] + bias;
        }
    }
}

// ---------------------------------------------------------------------------
extern "C" void kernel_launch(void* const* d_in, const int* in_sizes, int n_in,
                              void* d_out, int out_size, void* d_ws, size_t ws_size,
                              hipStream_t stream)
{
    const float* x   = (const float*)d_in[0];
    const float* w1  = (const float*)d_in[1];
    const float* b1  = (const float*)d_in[2];
    const float* g1  = (const float*)d_in[3];
    const float* be1 = (const float*)d_in[4];
    const float* ow  = (const float*)d_in[5];
    const float* ob  = (const float*)d_in[6];
    const float* dw  = (const float*)d_in[7];
    const float* db  = (const float*)d_in[8];
    const float* w2  = (const float*)d_in[9];
    const float* b2  = (const float*)d_in[10];
    const float* g2  = (const float*)d_in[11];
    const float* be2 = (const float*)d_in[12];
    float* out = (float*)d_out;

    float* ws    = (float*)d_ws;
    float* A     = ws;                           // conv1x1 out, BN'd in place
    float* offb  = A + (size_t)NPIX_ * 64;       // 1,327,104 floats
    float* w1t   = offb + (size_t)B_ * 18 * HW_;
    unsigned short* wkT = (unsigned short*)(w1t + 4096);   // 36,864 bf16
    float* beff  = (float*)(wkT + 9 * 4096);
    float* scsh1 = beff + 64;                    // 128
    float* scsh2 = scsh1 + 128;                  // 128
    unsigned short* Abf = (unsigned short*)(scsh2 + 128);  // NPIX_*64 bf16 (9.4MB)

    hipLaunchKernelGGL(k_fold, dim3(144), dim3(256), 0, stream,
                       w1, w2, dw, db, b2, w1t, wkT, beff);
    hipLaunchKernelGGL(k_conv1x1, dim3(NPIX_ / 64), dim3(256), 0, stream,
                       x, w1t, b1, A);
    hipLaunchKernelGGL(k_stats, dim3(64), dim3(256), 0, stream, A, g1, be1, scsh1);
    hipLaunchKernelGGL(k_bntr, dim3(NPIX_ / 128), dim3(256), 0, stream,
                       A, scsh1, Abf);
    hipLaunchKernelGGL(k_offconv, dim3(288), dim3(256), 0, stream,
                       A, ow, ob, offb);
    hipLaunchKernelGGL(k_deform, dim3(NPIX_ / 16), dim3(64), 0, stream,
                       Abf, offb, wkT, beff, out);
    hipLaunchKernelGGL(k_stats, dim3(64), dim3(256), 0, stream, out, g2, be2, scsh2);
    hipLaunchKernelGGL(k_bn, dim3((NPIX_ * 64 / 4) / 256), dim3(256), 0, stream,
                       out, scsh2, 0);
}

// Round 8
// 197.000 us; speedup vs baseline: 1.5225x; 1.2227x over previous
//
#include <hip/hip_runtime.h>
#include <math.h>

#define H_ 192
#define W_ 192
#define HW_ (H_*W_)      // 36864
#define B_ 2
#define C_ 64
#define NPIX_ (B_*HW_)   // 73728
#define EPSV 1e-5f

typedef short s8v  __attribute__((ext_vector_type(8)));
typedef float f4v  __attribute__((ext_vector_type(4)));

__device__ __forceinline__ unsigned short f2bf(float f) {
    union { float f; unsigned u; } x; x.f = f;
    unsigned r = x.u + 0x7fffu + ((x.u >> 16) & 1u);   // RNE
    return (unsigned short)(r >> 16);
}
__device__ __forceinline__ float bf2f(unsigned short h) {
    union { unsigned u; float f; } x; x.u = ((unsigned)h) << 16; return x.f;
}

// ---------------------------------------------------------------------------
// Fold: w1t[c][o] = w1[o][c];
//       wkT[k][p][c]  = bf16( sum_o w2[p,o]*dw[o,c,k] )   (deform weights)
//       wOff[k][oc32][c] = bf16( ow[oc][c][k] ), oc>=18 zero  (offconv weights)
//       beff[p] = sum_o w2[p,o]*db[o] + b2[p]
// ---------------------------------------------------------------------------
__global__ void k_fold(const float* __restrict__ w1, const float* __restrict__ w2,
                       const float* __restrict__ dw, const float* __restrict__ db,
                       const float* __restrict__ b2, const float* __restrict__ ow,
                       float* __restrict__ w1t, unsigned short* __restrict__ wkT,
                       unsigned short* __restrict__ wOff, float* __restrict__ beff)
{
    int tid = blockIdx.x * 256 + threadIdx.x;   // 0..36863
    if (tid < 9 * 64 * 64) {
        int k = tid >> 12;
        int r = tid & 4095;
        int c = r >> 6;
        int p = r & 63;
        float acc = 0.f;
        #pragma unroll 8
        for (int o = 0; o < 64; ++o)
            acc = fmaf(w2[p * 64 + o], dw[(o * 64 + c) * 9 + k], acc);
        wkT[(k << 12) + (p << 6) + c] = f2bf(acc);
    }
    if (tid < 9 * 32 * 64) {       // offconv weights, padded to 32 oc
        int k = tid >> 11;
        int r = tid & 2047;
        int oc = r >> 6;
        int c = r & 63;
        float v = (oc < 18) ? ow[((oc * 64) + c) * 9 + k] : 0.f;
        wOff[tid] = f2bf(v);
    }
    if (tid < 4096) {
        int c = tid >> 6, o = tid & 63;
        w1t[c * 64 + o] = w1[o * 64 + c];
    }
    if (tid < 64) {
        float acc = b2[tid];
        #pragma unroll 8
        for (int o = 0; o < 64; ++o) acc = fmaf(w2[tid * 64 + o], db[o], acc);
        beff[tid] = acc;
    }
}

// ---------------------------------------------------------------------------
// conv1x1 #1 (fp32 VALU): y = x * w1t + b1  (raw, pre-BN)
// ---------------------------------------------------------------------------
__global__ __launch_bounds__(256) void k_conv1x1(const float* __restrict__ x,
        const float* __restrict__ w1t, const float* __restrict__ b1,
        float* __restrict__ y)
{
    __shared__ __align__(16) float xs[64][64];   // [c][p]
    __shared__ __align__(16) float wsh[64][64];  // [c][o]
    int t = threadIdx.x;
    int base = blockIdx.x * 64;
    int b = base / HW_;
    int hw0 = base % HW_;

    #pragma unroll
    for (int i = 0; i < 16; ++i) {
        int e = t + i * 256;
        ((float*)wsh)[e] = w1t[e];
    }
    int p = t & 63, cg = t >> 6;
    #pragma unroll
    for (int i = 0; i < 16; ++i) {
        int c = cg * 16 + i;
        xs[c][p] = x[(b * 64 + c) * HW_ + hw0 + p];
    }
    __syncthreads();

    int l = t & 63, wv = t >> 6;
    int pg = l & 15;
    int og = wv * 4 + (l >> 4);
    float acc[4][4];
    #pragma unroll
    for (int i = 0; i < 4; ++i)
        #pragma unroll
        for (int j = 0; j < 4; ++j) acc[i][j] = 0.f;

    #pragma unroll 8
    for (int c = 0; c < 64; ++c) {
        float va[4], wa[4];
        *(float4*)va = *(const float4*)&xs[c][pg * 4];
        *(float4*)wa = *(const float4*)&wsh[c][og * 4];
        #pragma unroll
        for (int i = 0; i < 4; ++i)
            #pragma unroll
            for (int j = 0; j < 4; ++j)
                acc[i][j] = fmaf(va[i], wa[j], acc[i][j]);
    }

    #pragma unroll
    for (int j = 0; j < 4; ++j) {
        int oc = og * 4 + j;
        float bias = b1[oc];
        float4 o4 = make_float4(acc[0][j] + bias, acc[1][j] + bias,
                                acc[2][j] + bias, acc[3][j] + bias);
        *(float4*)&y[(b * 64 + oc) * HW_ + hw0 + pg * 4] = o4;
    }
}

// ---------------------------------------------------------------------------
// BN stats: one block per channel; writes scale, shift
// ---------------------------------------------------------------------------
__global__ void k_stats(const float* __restrict__ y, const float* __restrict__ g,
                        const float* __restrict__ be, float* __restrict__ scsh)
{
    int c = blockIdx.x;
    int t = threadIdx.x;
    float s = 0.f, sq = 0.f;
    for (int b = 0; b < B_; ++b) {
        const float4* p4 = (const float4*)&y[(b * 64 + c) * HW_];
        for (int i = t; i < HW_ / 4; i += 256) {
            float4 v = p4[i];
            s += v.x + v.y + v.z + v.w;
            sq += v.x * v.x + v.y * v.y + v.z * v.z + v.w * v.w;
        }
    }
    int lane = t & 63, wv = t >> 6;
    #pragma unroll
    for (int off = 32; off > 0; off >>= 1) {
        s += __shfl_down(s, off);
        sq += __shfl_down(sq, off);
    }
    __shared__ float red[8];
    if (lane == 0) { red[wv] = s; red[4 + wv] = sq; }
    __syncthreads();
    if (t == 0) {
        float S = red[0] + red[1] + red[2] + red[3];
        float Q = red[4] + red[5] + red[6] + red[7];
        float m = S / (float)NPIX_;
        float var = Q / (float)NPIX_ - m * m;
        float sc = g[c] * rsqrtf(var + EPSV);
        scsh[c] = sc;
        scsh[64 + c] = be[c] - m * sc;
    }
}

// ---------------------------------------------------------------------------
// BN apply, in place, float4 (used for final BN2 only)
// ---------------------------------------------------------------------------
__global__ void k_bn(float* __restrict__ y, const float* __restrict__ scsh, int relu)
{
    int idx = blockIdx.x * 256 + threadIdx.x;         // float4 index
    int c = ((idx * 4) / HW_) & 63;
    float sc = scsh[c], sh = scsh[64 + c];
    float4 v = ((float4*)y)[idx];
    v.x = fmaf(v.x, sc, sh);
    v.y = fmaf(v.y, sc, sh);
    v.z = fmaf(v.z, sc, sh);
    v.w = fmaf(v.w, sc, sh);
    if (relu) {
        v.x = fmaxf(v.x, 0.f); v.y = fmaxf(v.y, 0.f);
        v.z = fmaxf(v.z, 0.f); v.w = fmaxf(v.w, 0.f);
    }
    ((float4*)y)[idx] = v;
}

// ---------------------------------------------------------------------------
// BN1+ReLU -> bf16 NHWC copy ONLY (fp32 A stays raw; nothing consumes it
// downstream except stats, which already ran). Thread = 32 ch of one pixel.
// ---------------------------------------------------------------------------
__global__ __launch_bounds__(256) void k_bntr(const float* __restrict__ A,
        const float* __restrict__ scsh, unsigned short* __restrict__ Abf)
{
    __shared__ float scb[64], shb[64];
    int t = threadIdx.x;
    int wg = blockIdx.x;
    int nid = (wg & 7) * 72 + (wg >> 3);     // XCD-chunked over 576
    int base = nid * 128;                    // global pixel base
    int b = base / HW_;
    int hw0 = base % HW_;

    if (t < 64) { scb[t] = scsh[t]; shb[t] = scsh[64 + t]; }
    __syncthreads();

    int pl = t & 127;          // pixel within block
    int chalf = t >> 7;        // 0 or 1 -> channels 32*chalf..+32
    int hw = hw0 + pl;
    size_t gpx = (size_t)base + pl;

    unsigned pk[16];
    #pragma unroll
    for (int c = 0; c < 32; ++c) {
        int ch = chalf * 32 + c;
        size_t idx = ((size_t)(b * 64 + ch)) * HW_ + hw;
        float a = A[idx];
        float v = fmaxf(fmaf(a, scb[ch], shb[ch]), 0.f);
        unsigned bf = f2bf(v);
        if (c & 1) pk[c >> 1] |= bf << 16; else pk[c >> 1] = bf;
    }
    unsigned short* dst = Abf + (gpx << 6) + chalf * 32;
    #pragma unroll
    for (int j = 0; j < 4; ++j)
        *(int4*)&dst[j * 8] = make_int4((int)pk[4 * j], (int)pk[4 * j + 1],
                                        (int)pk[4 * j + 2], (int)pk[4 * j + 3]);
}

// ---------------------------------------------------------------------------
// offset conv3x3 via bf16 MFMA on Abf (NHWC): implicit GEMM, zero pad.
// 1 wave/block, 4608 blocks. Wave = 16px x 32oc (18 real). Per tap:
// 2 coalesced A loads (border-predicated to 0) + 4 W frags (L1) + 4 MFMAs.
// ---------------------------------------------------------------------------
__global__ __launch_bounds__(64) void k_offconv(const unsigned short* __restrict__ Abf,
        const unsigned short* __restrict__ wOff, const float* __restrict__ ob,
        float* __restrict__ off)
{
    int t = threadIdx.x;
    int wg = blockIdx.x;
    int nid = (wg & 7) * 576 + (wg >> 3);        // XCD-chunked over 4608
    int base = nid * 16;
    int b = base / HW_;
    int hw0 = base % HW_;
    int h = hw0 / W_;
    int w0 = hw0 % W_;

    int m = t & 15, q = t >> 4;
    int wx = w0 + m;
    const unsigned short* Ap = Abf + (((size_t)b * HW_) << 6);
    int cA = q * 8, cB = 32 + q * 8;

    f4v acc0 = (f4v){0.f, 0.f, 0.f, 0.f};
    f4v acc1 = (f4v){0.f, 0.f, 0.f, 0.f};
    const s8v zr = {0, 0, 0, 0, 0, 0, 0, 0};

    #pragma unroll
    for (int k = 0; k < 9; ++k) {
        int yy = h + k / 3 - 1;
        int xx = wx + k % 3 - 1;
        bool valid = (yy >= 0) && (yy < H_) && (xx >= 0) && (xx < W_);
        int yc = min(max(yy, 0), H_ - 1);
        int xc = min(max(xx, 0), W_ - 1);
        size_t ip = (size_t)(yc * W_ + xc) << 6;
        s8v a0 = *(const s8v*)&Ap[ip + cA];
        s8v a1 = *(const s8v*)&Ap[ip + cB];
        if (!valid) { a0 = zr; a1 = zr; }

        const unsigned short* wb = wOff + ((size_t)k << 11);
        s8v b00 = *(const s8v*)&wb[m * 64 + q * 8];
        s8v b01 = *(const s8v*)&wb[m * 64 + 32 + q * 8];
        s8v b10 = *(const s8v*)&wb[(16 + m) * 64 + q * 8];
        s8v b11 = *(const s8v*)&wb[(16 + m) * 64 + 32 + q * 8];

        acc0 = __builtin_amdgcn_mfma_f32_16x16x32_bf16(a0, b00, acc0, 0, 0, 0);
        acc0 = __builtin_amdgcn_mfma_f32_16x16x32_bf16(a1, b01, acc0, 0, 0, 0);
        acc1 = __builtin_amdgcn_mfma_f32_16x16x32_bf16(a0, b10, acc1, 0, 0, 0);
        acc1 = __builtin_amdgcn_mfma_f32_16x16x32_bf16(a1, b11, acc1, 0, 0, 0);
    }

    // epilogue: col(lane&15)=oc, row=(lane>>4)*4+reg=px
    float biasLo = ob[m];
    float biasHi = (m < 2) ? ob[16 + m] : 0.f;
    #pragma unroll
    for (int r = 0; r < 4; ++r) {
        int px = q * 4 + r;
        off[((size_t)b * 18 + m) * HW_ + hw0 + px] = acc0[r] + biasLo;
        if (m < 2)
            off[((size_t)b * 18 + 16 + m) * HW_ + hw0 + px] = acc1[r] + biasHi;
    }
}

// ---------------------------------------------------------------------------
// deformable conv via bf16 MFMA — 1 wave/block, software-pipelined taps.
// ---------------------------------------------------------------------------
#define ISSUE(KK, SS) {                                                        \
    float py = (float)(h + (KK) / 3 - 1) + ofy[KK];                            \
    float px = (float)(wx + (KK) % 3 - 1) + ofx[KK];                           \
    float fly = floorf(py), flx = floorf(px);                                  \
    float fy = py - fly, fx = px - flx;                                        \
    int y0i = (int)fly, x0i = (int)flx;                                        \
    float w00 = (1.f - fy) * (1.f - fx);                                       \
    float w01 = (1.f - fy) * fx;                                               \
    float w10 = fy * (1.f - fx);                                               \
    float w11 = fy * fx;                                                       \
    bool yv0 = (y0i >= 0) && (y0i < H_);                                       \
    bool yv1 = (y0i + 1 >= 0) && (y0i + 1 < H_);                               \
    bool xv0 = (x0i >= 0) && (x0i < W_);                                       \
    bool xv1 = (x0i + 1 >= 0) && (x0i + 1 < W_);                               \
    if (!(yv0 && xv0)) w00 = 0.f;                                              \
    if (!(yv0 && xv1)) w01 = 0.f;                                              \
    if (!(yv1 && xv0)) w10 = 0.f;                                              \
    if (!(yv1 && xv1)) w11 = 0.f;                                              \
    int yc0 = min(max(y0i, 0), H_ - 1), yc1 = min(max(y0i + 1, 0), H_ - 1);    \
    int xc0 = min(max(x0i, 0), W_ - 1), xc1 = min(max(x0i + 1, 0), W_ - 1);    \
    size_t i00 = (size_t)(yc0 * W_ + xc0) << 6;                                \
    size_t i01 = (size_t)(yc0 * W_ + xc1) << 6;                                \
    size_t i10 = (size_t)(yc1 * W_ + xc0) << 6;                                \
    size_t i11 = (size_t)(yc1 * W_ + xc1) << 6;                                \
    g00a[SS] = *(const s8v*)&Ap[i00 + cA];                                     \
    g01a[SS] = *(const s8v*)&Ap[i01 + cA];                                     \
    g10a[SS] = *(const s8v*)&Ap[i10 + cA];                                     \
    g11a[SS] = *(const s8v*)&Ap[i11 + cA];                                     \
    g00b[SS] = *(const s8v*)&Ap[i00 + cB];                                     \
    g01b[SS] = *(const s8v*)&Ap[i01 + cB];                                     \
    g10b[SS] = *(const s8v*)&Ap[i10 + cB];                                     \
    g11b[SS] = *(const s8v*)&Ap[i11 + cB];                                     \
    wq0[SS] = w00; wq1[SS] = w01; wq2[SS] = w10; wq3[SS] = w11; }

__global__ __launch_bounds__(64) void k_deform(const unsigned short* __restrict__ Abf,
        const float* __restrict__ off,
        const unsigned short* __restrict__ wkT, const float* __restrict__ beff,
        float* __restrict__ out)
{
    int t = threadIdx.x;
    int wg = blockIdx.x;
    int nid = (wg & 7) * 576 + (wg >> 3);        // XCD-chunked over 4608
    int base = nid * 16;                         // 16-px tile
    int b = base / HW_;
    int hw0 = base % HW_;
    int h = hw0 / W_;
    int w0 = hw0 % W_;

    int m = t & 15, q = t >> 4;
    int hw = hw0 + m;                // this lane's pixel
    int wx = w0 + m;

    const unsigned short* Ap = Abf + (((size_t)b * HW_) << 6);
    int cA = q * 8, cB = 32 + q * 8;

    // ---- all 18 offsets upfront: one memory round trip
    float ofy[9], ofx[9];
    #pragma unroll
    for (int k = 0; k < 9; ++k) {
        ofy[k] = off[((b * 18) + 2 * k) * HW_ + hw];
        ofx[k] = off[((b * 18) + 2 * k + 1) * HW_ + hw];
    }

    f4v acc[4];
    #pragma unroll
    for (int n = 0; n < 4; ++n) acc[n] = (f4v){0.f, 0.f, 0.f, 0.f};

    // ---- gather double buffer (indices constant after full unroll)
    s8v g00a[2], g01a[2], g10a[2], g11a[2];
    s8v g00b[2], g01b[2], g10b[2], g11b[2];
    float wq0[2], wq1[2], wq2[2], wq3[2];

    ISSUE(0, 0);

    #pragma unroll
    for (int k = 0; k < 9; ++k) {
        const int cur = k & 1;
        const int nxt = cur ^ 1;
        if (k < 8) {
            switch (k + 1) {     // keep KK a literal constant for addressing
                case 1: ISSUE(1, nxt); break;
                case 2: ISSUE(2, nxt); break;
                case 3: ISSUE(3, nxt); break;
                case 4: ISSUE(4, nxt); break;
                case 5: ISSUE(5, nxt); break;
                case 6: ISSUE(6, nxt); break;
                case 7: ISSUE(7, nxt); break;
                case 8: ISSUE(8, nxt); break;
            }
        }

        // ---- W fragments for tap k (L1/L2-resident)
        const unsigned short* wkb = wkT + ((size_t)k << 12);
        s8v wb0[4], wb1[4];
        #pragma unroll
        for (int n = 0; n < 4; ++n) {
            int oc = n * 16 + m;
            wb0[n] = *(const s8v*)&wkb[oc * 64 + q * 8];
            wb1[n] = *(const s8v*)&wkb[oc * 64 + 32 + q * 8];
        }

        // ---- interp (fp32 on bf16 corners) + pack to bf16 fragments
        float w00 = wq0[cur], w01 = wq1[cur], w10 = wq2[cur], w11 = wq3[cur];
        unsigned ua[4], ub[4];
        #pragma unroll
        for (int i = 0; i < 4; ++i) {
            unsigned wa = 0, wbv = 0;
            #pragma unroll
            for (int jj = 0; jj < 2; ++jj) {
                int e = 2 * i + jj;
                float va = bf2f((unsigned short)g00a[cur][e]) * w00
                         + bf2f((unsigned short)g01a[cur][e]) * w01
                         + bf2f((unsigned short)g10a[cur][e]) * w10
                         + bf2f((unsigned short)g11a[cur][e]) * w11;
                wa |= ((unsigned)f2bf(va)) << (16 * jj);
                float vb = bf2f((unsigned short)g00b[cur][e]) * w00
                         + bf2f((unsigned short)g01b[cur][e]) * w01
                         + bf2f((unsigned short)g10b[cur][e]) * w10
                         + bf2f((unsigned short)g11b[cur][e]) * w11;
                wbv |= ((unsigned)f2bf(vb)) << (16 * jj);
            }
            ua[i] = wa; ub[i] = wbv;
        }
        union { unsigned u[4]; s8v v; } fa, fb;
        fa.u[0] = ua[0]; fa.u[1] = ua[1]; fa.u[2] = ua[2]; fa.u[3] = ua[3];
        fb.u[0] = ub[0]; fb.u[1] = ub[1]; fb.u[2] = ub[2]; fb.u[3] = ub[3];

        // ---- 8 MFMAs
        #pragma unroll
        for (int n = 0; n < 4; ++n) {
            acc[n] = __builtin_amdgcn_mfma_f32_16x16x32_bf16(fa.v, wb0[n], acc[n], 0, 0, 0);
            acc[n] = __builtin_amdgcn_mfma_f32_16x16x32_bf16(fb.v, wb1[n], acc[n], 0, 0, 0);
        }
    }

    // ---- epilogue: C/D layout col(lane&15)=oc-offset m, row=(lane>>4)*4+reg=px
    #pragma unroll
    for (int n = 0; n < 4; ++n) {
        int oc = n * 16 + m;
        float bias = beff[oc];
        #pragma unroll
        for (int r = 0; r < 4; ++r) {
            int pxr = q * 4 + r;
            out[((size_t)b * 64 + oc) * HW_ + hw0 + pxr] = acc[n][r] + bias;
        }
    }
}

// ---------------------------------------------------------------------------
extern "C" void kernel_launch(void* const* d_in, const int* in_sizes, int n_in,
                              void* d_out, int out_size, void* d_ws, size_t ws_size,
                              hipStream_t stream)
{
    const float* x   = (const float*)d_in[0];
    const float* w1  = (const float*)d_in[1];
    const float* b1  = (const float*)d_in[2];
    const float* g1  = (const float*)d_in[3];
    const float* be1 = (const float*)d_in[4];
    const float* ow  = (const float*)d_in[5];
    const float* ob  = (const float*)d_in[6];
    const float* dw  = (const float*)d_in[7];
    const float* db  = (const float*)d_in[8];
    const float* w2  = (const float*)d_in[9];
    const float* b2  = (const float*)d_in[10];
    const float* g2  = (const float*)d_in[11];
    const float* be2 = (const float*)d_in[12];
    float* out = (float*)d_out;

    float* ws    = (float*)d_ws;
    float* A     = ws;                           // conv1x1 out (raw fp32)
    float* offb  = A + (size_t)NPIX_ * 64;       // 1,327,104 floats
    float* w1t   = offb + (size_t)B_ * 18 * HW_;
    unsigned short* wkT  = (unsigned short*)(w1t + 4096);   // 36,864 bf16
    unsigned short* wOff = wkT + 9 * 4096;                   // 18,432 bf16
    float* beff  = (float*)(wOff + 9 * 2048);
    float* scsh1 = beff + 64;                    // 128
    float* scsh2 = scsh1 + 128;                  // 128
    unsigned short* Abf = (unsigned short*)(scsh2 + 128);  // NPIX_*64 bf16

    hipLaunchKernelGGL(k_fold, dim3(144), dim3(256), 0, stream,
                       w1, w2, dw, db, b2, ow, w1t, wkT, wOff, beff);
    hipLaunchKernelGGL(k_conv1x1, dim3(NPIX_ / 64), dim3(256), 0, stream,
                       x, w1t, b1, A);
    hipLaunchKernelGGL(k_stats, dim3(64), dim3(256), 0, stream, A, g1, be1, scsh1);
    hipLaunchKernelGGL(k_bntr, dim3(NPIX_ / 128), dim3(256), 0, stream,
                       A, scsh1, Abf);
    hipLaunchKernelGGL(k_offconv, dim3(NPIX_ / 16), dim3(64), 0, stream,
                       Abf, wOff, ob, offb);
    hipLaunchKernelGGL(k_deform, dim3(NPIX_ / 16), dim3(64), 0, stream,
                       Abf, offb, wkT, beff, out);
    hipLaunchKernelGGL(k_stats, dim3(64), dim3(256), 0, stream, out, g2, be2, scsh2);
    hipLaunchKernelGGL(k_bn, dim3((NPIX_ * 64 / 4) / 256), dim3(256), 0, stream,
                       out, scsh2, 0);
}

// Round 10
// 196.522 us; speedup vs baseline: 1.5262x; 1.0024x over previous
//
#include <hip/hip_runtime.h>
#include <math.h>

#define H_ 192
#define W_ 192
#define HW_ (H_*W_)      // 36864
#define B_ 2
#define C_ 64
#define NPIX_ (B_*HW_)   // 73728
#define EPSV 1e-5f

typedef short s8v  __attribute__((ext_vector_type(8)));
typedef float f4v  __attribute__((ext_vector_type(4)));

__device__ __forceinline__ unsigned short f2bf(float f) {
    union { float f; unsigned u; } x; x.f = f;
    unsigned r = x.u + 0x7fffu + ((x.u >> 16) & 1u);   // RNE
    return (unsigned short)(r >> 16);
}
__device__ __forceinline__ float bf2f(unsigned short h) {
    union { unsigned u; float f; } x; x.u = ((unsigned)h) << 16; return x.f;
}

// ---------------------------------------------------------------------------
// Fold: w1t[c][o] = w1[o][c];
//       wkT[k][p][c]  = bf16( sum_o w2[p,o]*dw[o,c,k] )   (deform weights)
//       wOff[k][oc32][c] = bf16( ow[oc][c][k] ), oc>=18 zero  (offconv weights)
//       beff[p] = sum_o w2[p,o]*db[o] + b2[p]
// ---------------------------------------------------------------------------
__global__ void k_fold(const float* __restrict__ w1, const float* __restrict__ w2,
                       const float* __restrict__ dw, const float* __restrict__ db,
                       const float* __restrict__ b2, const float* __restrict__ ow,
                       float* __restrict__ w1t, unsigned short* __restrict__ wkT,
                       unsigned short* __restrict__ wOff, float* __restrict__ beff)
{
    int tid = blockIdx.x * 256 + threadIdx.x;   // 0..36863
    if (tid < 9 * 64 * 64) {
        int k = tid >> 12;
        int r = tid & 4095;
        int c = r >> 6;
        int p = r & 63;
        float acc = 0.f;
        #pragma unroll 8
        for (int o = 0; o < 64; ++o)
            acc = fmaf(w2[p * 64 + o], dw[(o * 64 + c) * 9 + k], acc);
        wkT[(k << 12) + (p << 6) + c] = f2bf(acc);
    }
    if (tid < 9 * 32 * 64) {       // offconv weights, padded to 32 oc
        int k = tid >> 11;
        int r = tid & 2047;
        int oc = r >> 6;
        int c = r & 63;
        float v = (oc < 18) ? ow[((oc * 64) + c) * 9 + k] : 0.f;
        wOff[tid] = f2bf(v);
    }
    if (tid < 4096) {
        int c = tid >> 6, o = tid & 63;
        w1t[c * 64 + o] = w1[o * 64 + c];
    }
    if (tid < 64) {
        float acc = b2[tid];
        #pragma unroll 8
        for (int o = 0; o < 64; ++o) acc = fmaf(w2[tid * 64 + o], db[o], acc);
        beff[tid] = acc;
    }
}

// ---------------------------------------------------------------------------
// conv1x1 #1 (fp32 VALU): y = x * w1t + b1  (raw, pre-BN)
// ---------------------------------------------------------------------------
__global__ __launch_bounds__(256) void k_conv1x1(const float* __restrict__ x,
        const float* __restrict__ w1t, const float* __restrict__ b1,
        float* __restrict__ y)
{
    __shared__ __align__(16) float xs[64][64];   // [c][p]
    __shared__ __align__(16) float wsh[64][64];  // [c][o]
    int t = threadIdx.x;
    int base = blockIdx.x * 64;
    int b = base / HW_;
    int hw0 = base % HW_;

    #pragma unroll
    for (int i = 0; i < 16; ++i) {
        int e = t + i * 256;
        ((float*)wsh)[e] = w1t[e];
    }
    int p = t & 63, cg = t >> 6;
    #pragma unroll
    for (int i = 0; i < 16; ++i) {
        int c = cg * 16 + i;
        xs[c][p] = x[(b * 64 + c) * HW_ + hw0 + p];
    }
    __syncthreads();

    int l = t & 63, wv = t >> 6;
    int pg = l & 15;
    int og = wv * 4 + (l >> 4);
    float acc[4][4];
    #pragma unroll
    for (int i = 0; i < 4; ++i)
        #pragma unroll
        for (int j = 0; j < 4; ++j) acc[i][j] = 0.f;

    #pragma unroll 8
    for (int c = 0; c < 64; ++c) {
        float va[4], wa[4];
        *(float4*)va = *(const float4*)&xs[c][pg * 4];
        *(float4*)wa = *(const float4*)&wsh[c][og * 4];
        #pragma unroll
        for (int i = 0; i < 4; ++i)
            #pragma unroll
            for (int j = 0; j < 4; ++j)
                acc[i][j] = fmaf(va[i], wa[j], acc[i][j]);
    }

    #pragma unroll
    for (int j = 0; j < 4; ++j) {
        int oc = og * 4 + j;
        float bias = b1[oc];
        float4 o4 = make_float4(acc[0][j] + bias, acc[1][j] + bias,
                                acc[2][j] + bias, acc[3][j] + bias);
        *(float4*)&y[(b * 64 + oc) * HW_ + hw0 + pg * 4] = o4;
    }
}

// ---------------------------------------------------------------------------
// BN stats: one block per channel; writes scale, shift
// ---------------------------------------------------------------------------
__global__ void k_stats(const float* __restrict__ y, const float* __restrict__ g,
                        const float* __restrict__ be, float* __restrict__ scsh)
{
    int c = blockIdx.x;
    int t = threadIdx.x;
    float s = 0.f, sq = 0.f;
    for (int b = 0; b < B_; ++b) {
        const float4* p4 = (const float4*)&y[(b * 64 + c) * HW_];
        for (int i = t; i < HW_ / 4; i += 256) {
            float4 v = p4[i];
            s += v.x + v.y + v.z + v.w;
            sq += v.x * v.x + v.y * v.y + v.z * v.z + v.w * v.w;
        }
    }
    int lane = t & 63, wv = t >> 6;
    #pragma unroll
    for (int off = 32; off > 0; off >>= 1) {
        s += __shfl_down(s, off);
        sq += __shfl_down(sq, off);
    }
    __shared__ float red[8];
    if (lane == 0) { red[wv] = s; red[4 + wv] = sq; }
    __syncthreads();
    if (t == 0) {
        float S = red[0] + red[1] + red[2] + red[3];
        float Q = red[4] + red[5] + red[6] + red[7];
        float m = S / (float)NPIX_;
        float var = Q / (float)NPIX_ - m * m;
        float sc = g[c] * rsqrtf(var + EPSV);
        scsh[c] = sc;
        scsh[64 + c] = be[c] - m * sc;
    }
}

// ---------------------------------------------------------------------------
// BN apply, in place, float4 (used for final BN2 only)
// ---------------------------------------------------------------------------
__global__ void k_bn(float* __restrict__ y, const float* __restrict__ scsh, int relu)
{
    int idx = blockIdx.x * 256 + threadIdx.x;         // float4 index
    int c = ((idx * 4) / HW_) & 63;
    float sc = scsh[c], sh = scsh[64 + c];
    float4 v = ((float4*)y)[idx];
    v.x = fmaf(v.x, sc, sh);
    v.y = fmaf(v.y, sc, sh);
    v.z = fmaf(v.z, sc, sh);
    v.w = fmaf(v.w, sc, sh);
    if (relu) {
        v.x = fmaxf(v.x, 0.f); v.y = fmaxf(v.y, 0.f);
        v.z = fmaxf(v.z, 0.f); v.w = fmaxf(v.w, 0.f);
    }
    ((float4*)y)[idx] = v;
}

// ---------------------------------------------------------------------------
// BN1+ReLU -> bf16 NHWC copy ONLY. Thread = 32 ch of one pixel.
// ---------------------------------------------------------------------------
__global__ __launch_bounds__(256) void k_bntr(const float* __restrict__ A,
        const float* __restrict__ scsh, unsigned short* __restrict__ Abf)
{
    __shared__ float scb[64], shb[64];
    int t = threadIdx.x;
    int wg = blockIdx.x;
    int nid = (wg & 7) * 72 + (wg >> 3);     // XCD-chunked over 576
    int base = nid * 128;                    // global pixel base
    int b = base / HW_;
    int hw0 = base % HW_;

    if (t < 64) { scb[t] = scsh[t]; shb[t] = scsh[64 + t]; }
    __syncthreads();

    int pl = t & 127;          // pixel within block
    int chalf = t >> 7;        // 0 or 1 -> channels 32*chalf..+32
    int hw = hw0 + pl;
    size_t gpx = (size_t)base + pl;

    unsigned pk[16];
    #pragma unroll
    for (int c = 0; c < 32; ++c) {
        int ch = chalf * 32 + c;
        size_t idx = ((size_t)(b * 64 + ch)) * HW_ + hw;
        float a = A[idx];
        float v = fmaxf(fmaf(a, scb[ch], shb[ch]), 0.f);
        unsigned bf = f2bf(v);
        if (c & 1) pk[c >> 1] |= bf << 16; else pk[c >> 1] = bf;
    }
    unsigned short* dst = Abf + (gpx << 6) + chalf * 32;
    #pragma unroll
    for (int j = 0; j < 4; ++j)
        *(int4*)&dst[j * 8] = make_int4((int)pk[4 * j], (int)pk[4 * j + 1],
                                        (int)pk[4 * j + 2], (int)pk[4 * j + 3]);
}

// ---------------------------------------------------------------------------
// offset conv3x3 via bf16 MFMA on Abf (NHWC): implicit GEMM, zero pad.
// ---------------------------------------------------------------------------
__global__ __launch_bounds__(64) void k_offconv(const unsigned short* __restrict__ Abf,
        const unsigned short* __restrict__ wOff, const float* __restrict__ ob,
        float* __restrict__ off)
{
    int t = threadIdx.x;
    int wg = blockIdx.x;
    int nid = (wg & 7) * 576 + (wg >> 3);        // XCD-chunked over 4608
    int base = nid * 16;
    int b = base / HW_;
    int hw0 = base % HW_;
    int h = hw0 / W_;
    int w0 = hw0 % W_;

    int m = t & 15, q = t >> 4;
    int wx = w0 + m;
    const unsigned short* Ap = Abf + (((size_t)b * HW_) << 6);
    int cA = q * 8, cB = 32 + q * 8;

    f4v acc0 = (f4v){0.f, 0.f, 0.f, 0.f};
    f4v acc1 = (f4v){0.f, 0.f, 0.f, 0.f};
    const s8v zr = {0, 0, 0, 0, 0, 0, 0, 0};

    #pragma unroll
    for (int k = 0; k < 9; ++k) {
        int yy = h + k / 3 - 1;
        int xx = wx + k % 3 - 1;
        bool valid = (yy >= 0) && (yy < H_) && (xx >= 0) && (xx < W_);
        int yc = min(max(yy, 0), H_ - 1);
        int xc = min(max(xx, 0), W_ - 1);
        size_t ip = (size_t)(yc * W_ + xc) << 6;
        s8v a0 = *(const s8v*)&Ap[ip + cA];
        s8v a1 = *(const s8v*)&Ap[ip + cB];
        if (!valid) { a0 = zr; a1 = zr; }

        const unsigned short* wb = wOff + ((size_t)k << 11);
        s8v b00 = *(const s8v*)&wb[m * 64 + q * 8];
        s8v b01 = *(const s8v*)&wb[m * 64 + 32 + q * 8];
        s8v b10 = *(const s8v*)&wb[(16 + m) * 64 + q * 8];
        s8v b11 = *(const s8v*)&wb[(16 + m) * 64 + 32 + q * 8];

        acc0 = __builtin_amdgcn_mfma_f32_16x16x32_bf16(a0, b00, acc0, 0, 0, 0);
        acc0 = __builtin_amdgcn_mfma_f32_16x16x32_bf16(a1, b01, acc0, 0, 0, 0);
        acc1 = __builtin_amdgcn_mfma_f32_16x16x32_bf16(a0, b10, acc1, 0, 0, 0);
        acc1 = __builtin_amdgcn_mfma_f32_16x16x32_bf16(a1, b11, acc1, 0, 0, 0);
    }

    float biasLo = ob[m];
    float biasHi = (m < 2) ? ob[16 + m] : 0.f;
    #pragma unroll
    for (int r = 0; r < 4; ++r) {
        int px = q * 4 + r;
        off[((size_t)b * 18 + m) * HW_ + hw0 + px] = acc0[r] + biasLo;
        if (m < 2)
            off[((size_t)b * 18 + 16 + m) * HW_ + hw0 + px] = acc1[r] + biasHi;
    }
}

// ---------------------------------------------------------------------------
// deformable conv via bf16 MFMA — 4 waves/block, no LDS/barriers.
// vmcnt-ordered pipeline: ISSUE(k+1) emits gathers AND W-fragments for tap
// k+1 BEFORE tap k is consumed; no loads between issue and consume, so the
// compiler's waitcnt for tap-k data leaves the 24 tap-(k+1) loads in flight.
// ---------------------------------------------------------------------------
#define ISSUE(KK, SS) {                                                        \
    float py = (float)(h + (KK) / 3 - 1) + ofy[KK];                            \
    float px = (float)(wx + (KK) % 3 - 1) + ofx[KK];                           \
    float fly = floorf(py), flx = floorf(px);                                  \
    float fy = py - fly, fx = px - flx;                                        \
    int y0i = (int)fly, x0i = (int)flx;                                        \
    float w00 = (1.f - fy) * (1.f - fx);                                       \
    float w01 = (1.f - fy) * fx;                                               \
    float w10 = fy * (1.f - fx);                                               \
    float w11 = fy * fx;                                                       \
    bool yv0 = (y0i >= 0) && (y0i < H_);                                       \
    bool yv1 = (y0i + 1 >= 0) && (y0i + 1 < H_);                               \
    bool xv0 = (x0i >= 0) && (x0i < W_);                                       \
    bool xv1 = (x0i + 1 >= 0) && (x0i + 1 < W_);                               \
    if (!(yv0 && xv0)) w00 = 0.f;                                              \
    if (!(yv0 && xv1)) w01 = 0.f;                                              \
    if (!(yv1 && xv0)) w10 = 0.f;                                              \
    if (!(yv1 && xv1)) w11 = 0.f;                                              \
    int yc0 = min(max(y0i, 0), H_ - 1), yc1 = min(max(y0i + 1, 0), H_ - 1);    \
    int xc0 = min(max(x0i, 0), W_ - 1), xc1 = min(max(x0i + 1, 0), W_ - 1);    \
    size_t i00 = (size_t)(yc0 * W_ + xc0) << 6;                                \
    size_t i01 = (size_t)(yc0 * W_ + xc1) << 6;                                \
    size_t i10 = (size_t)(yc1 * W_ + xc0) << 6;                                \
    size_t i11 = (size_t)(yc1 * W_ + xc1) << 6;                                \
    g00a[SS] = *(const s8v*)&Ap[i00 + cA];                                     \
    g01a[SS] = *(const s8v*)&Ap[i01 + cA];                                     \
    g10a[SS] = *(const s8v*)&Ap[i10 + cA];                                     \
    g11a[SS] = *(const s8v*)&Ap[i11 + cA];                                     \
    g00b[SS] = *(const s8v*)&Ap[i00 + cB];                                     \
    g01b[SS] = *(const s8v*)&Ap[i01 + cB];                                     \
    g10b[SS] = *(const s8v*)&Ap[i10 + cB];                                     \
    g11b[SS] = *(const s8v*)&Ap[i11 + cB];                                     \
    {                                                                          \
        const unsigned short* wkb = wkT + ((size_t)(KK) << 12);                \
        _Pragma("unroll")                                                      \
        for (int n = 0; n < 4; ++n) {                                          \
            int oc = n * 16 + m;                                               \
            wf0[SS][n] = *(const s8v*)&wkb[oc * 64 + q * 8];                   \
            wf1[SS][n] = *(const s8v*)&wkb[oc * 64 + 32 + q * 8];              \
        }                                                                      \
    }                                                                          \
    wq0[SS] = w00; wq1[SS] = w01; wq2[SS] = w10; wq3[SS] = w11; }

__global__ __launch_bounds__(256) void k_deform(const unsigned short* __restrict__ Abf,
        const float* __restrict__ off,
        const unsigned short* __restrict__ wkT, const float* __restrict__ beff,
        float* __restrict__ out)
{
    int t = threadIdx.x;
    int wg = blockIdx.x;
    int nid = (wg & 7) * 144 + (wg >> 3);        // XCD-chunked over 1152
    int base = nid * 64;                         // 64-px block tile
    int b = base / HW_;
    int hw0b = base % HW_;

    int wv = t >> 6;
    int lane = t & 63;
    int m = lane & 15, q = lane >> 4;
    int hw0 = hw0b + wv * 16;        // this wave's 16-px tile (within image)
    int h = hw0 / W_;                // FIX(R9): derive from within-image index
    int w0 = hw0 % W_;
    int hw = hw0 + m;
    int wx = w0 + m;

    const unsigned short* Ap = Abf + (((size_t)b * HW_) << 6);
    int cA = q * 8, cB = 32 + q * 8;

    // ---- all 18 offsets upfront: one memory round trip
    float ofy[9], ofx[9];
    #pragma unroll
    for (int k = 0; k < 9; ++k) {
        ofy[k] = off[((b * 18) + 2 * k) * HW_ + hw];
        ofx[k] = off[((b * 18) + 2 * k + 1) * HW_ + hw];
    }

    f4v acc[4];
    #pragma unroll
    for (int n = 0; n < 4; ++n) acc[n] = (f4v){0.f, 0.f, 0.f, 0.f};

    // ---- double buffers: gathers + W fragments + bilinear weights
    s8v g00a[2], g01a[2], g10a[2], g11a[2];
    s8v g00b[2], g01b[2], g10b[2], g11b[2];
    s8v wf0[2][4], wf1[2][4];
    float wq0[2], wq1[2], wq2[2], wq3[2];

    ISSUE(0, 0);

    #pragma unroll
    for (int k = 0; k < 9; ++k) {
        const int cur = k & 1;
        const int nxt = cur ^ 1;
        if (k < 8) {
            switch (k + 1) {     // keep KK a literal constant
                case 1: ISSUE(1, nxt); break;
                case 2: ISSUE(2, nxt); break;
                case 3: ISSUE(3, nxt); break;
                case 4: ISSUE(4, nxt); break;
                case 5: ISSUE(5, nxt); break;
                case 6: ISSUE(6, nxt); break;
                case 7: ISSUE(7, nxt); break;
                case 8: ISSUE(8, nxt); break;
            }
        }

        // ---- consume tap k: interp (fp32 on bf16 corners) + pack + MFMA.
        // No loads issued below this point within the iteration.
        float w00 = wq0[cur], w01 = wq1[cur], w10 = wq2[cur], w11 = wq3[cur];
        unsigned ua[4], ub[4];
        #pragma unroll
        for (int i = 0; i < 4; ++i) {
            unsigned wa = 0, wbv = 0;
            #pragma unroll
            for (int jj = 0; jj < 2; ++jj) {
                int e = 2 * i + jj;
                float va = bf2f((unsigned short)g00a[cur][e]) * w00
                         + bf2f((unsigned short)g01a[cur][e]) * w01
                         + bf2f((unsigned short)g10a[cur][e]) * w10
                         + bf2f((unsigned short)g11a[cur][e]) * w11;
                wa |= ((unsigned)f2bf(va)) << (16 * jj);
                float vb = bf2f((unsigned short)g00b[cur][e]) * w00
                         + bf2f((unsigned short)g01b[cur][e]) * w01
                         + bf2f((unsigned short)g10b[cur][e]) * w10
                         + bf2f((unsigned short)g11b[cur][e]) * w11;
                wbv |= ((unsigned)f2bf(vb)) << (16 * jj);
            }
            ua[i] = wa; ub[i] = wbv;
        }
        union { unsigned u[4]; s8v v; } fa, fb;
        fa.u[0] = ua[0]; fa.u[1] = ua[1]; fa.u[2] = ua[2]; fa.u[3] = ua[3];
        fb.u[0] = ub[0]; fb.u[1] = ub[1]; fb.u[2] = ub[2]; fb.u[3] = ub[3];

        #pragma unroll
        for (int n = 0; n < 4; ++n) {
            acc[n] = __builtin_amdgcn_mfma_f32_16x16x32_bf16(fa.v, wf0[cur][n], acc[n], 0, 0, 0);
            acc[n] = __builtin_amdgcn_mfma_f32_16x16x32_bf16(fb.v, wf1[cur][n], acc[n], 0, 0, 0);
        }
    }

    // ---- epilogue: C/D layout col(lane&15)=oc-offset m, row=(lane>>4)*4+reg=px
    #pragma unroll
    for (int n = 0; n < 4; ++n) {
        int oc = n * 16 + m;
        float bias = beff[oc];
        #pragma unroll
        for (int r = 0; r < 4; ++r) {
            int pxr = q * 4 + r;
            out[((size_t)b * 64 + oc) * HW_ + hw0 + pxr] = acc[n][r] + bias;
        }
    }
}

// ---------------------------------------------------------------------------
extern "C" void kernel_launch(void* const* d_in, const int* in_sizes, int n_in,
                              void* d_out, int out_size, void* d_ws, size_t ws_size,
                              hipStream_t stream)
{
    const float* x   = (const float*)d_in[0];
    const float* w1  = (const float*)d_in[1];
    const float* b1  = (const float*)d_in[2];
    const float* g1  = (const float*)d_in[3];
    const float* be1 = (const float*)d_in[4];
    const float* ow  = (const float*)d_in[5];
    const float* ob  = (const float*)d_in[6];
    const float* dw  = (const float*)d_in[7];
    const float* db  = (const float*)d_in[8];
    const float* w2  = (const float*)d_in[9];
    const float* b2  = (const float*)d_in[10];
    const float* g2  = (const float*)d_in[11];
    const float* be2 = (const float*)d_in[12];
    float* out = (float*)d_out;

    float* ws    = (float*)d_ws;
    float* A     = ws;                           // conv1x1 out (raw fp32)
    float* offb  = A + (size_t)NPIX_ * 64;       // 1,327,104 floats
    float* w1t   = offb + (size_t)B_ * 18 * HW_;
    unsigned short* wkT  = (unsigned short*)(w1t + 4096);   // 36,864 bf16
    unsigned short* wOff = wkT + 9 * 4096;                   // 18,432 bf16
    float* beff  = (float*)(wOff + 9 * 2048);
    float* scsh1 = beff + 64;                    // 128
    float* scsh2 = scsh1 + 128;                  // 128
    unsigned short* Abf = (unsigned short*)(scsh2 + 128);  // NPIX_*64 bf16

    hipLaunchKernelGGL(k_fold, dim3(144), dim3(256), 0, stream,
                       w1, w2, dw, db, b2, ow, w1t, wkT, wOff, beff);
    hipLaunchKernelGGL(k_conv1x1, dim3(NPIX_ / 64), dim3(256), 0, stream,
                       x, w1t, b1, A);
    hipLaunchKernelGGL(k_stats, dim3(64), dim3(256), 0, stream, A, g1, be1, scsh1);
    hipLaunchKernelGGL(k_bntr, dim3(NPIX_ / 128), dim3(256), 0, stream,
                       A, scsh1, Abf);
    hipLaunchKernelGGL(k_offconv, dim3(NPIX_ / 16), dim3(64), 0, stream,
                       Abf, wOff, ob, offb);
    hipLaunchKernelGGL(k_deform, dim3(NPIX_ / 64), dim3(256), 0, stream,
                       Abf, offb, wkT, beff, out);
    hipLaunchKernelGGL(k_stats, dim3(64), dim3(256), 0, stream, out, g2, be2, scsh2);
    hipLaunchKernelGGL(k_bn, dim3((NPIX_ * 64 / 4) / 256), dim3(256), 0, stream,
                       out, scsh2, 0);
}